// Round 9
// baseline (510.249 us; speedup 1.0000x reference)
//
#include <hip/hip_runtime.h>
#include <hip/hip_bf16.h>
#include <stdint.h>

// Problem constants (fixed by the reference)
#define B_    4
#define N_    2048
#define DIM_  1024
#define H_    8
#define HD_   128
#define MTOK  (B_ * N_)          // 8192 tokens
#define SCALE_  0.08838834764831845f   // HD^-0.5
#define LOG2E_  1.4426950408889634f
#define QSCALE_ (SCALE_ * LOG2E_)      // folded into Q projection epilogue

typedef unsigned short u16;
typedef __attribute__((ext_vector_type(4)))  float f32x4;
typedef __attribute__((ext_vector_type(16))) float f32x16;
typedef __attribute__((ext_vector_type(8)))  short s16x8;   // 8 bf16 — MFMA A/B frag
typedef __attribute__((ext_vector_type(8)))  u16  u16x8;
typedef __attribute__((ext_vector_type(4)))  u16  u16x4;
typedef __attribute__((ext_vector_type(4)))  unsigned u32x4;

__device__ __forceinline__ u16 f2bf(float f) {
    uint32_t i = __builtin_bit_cast(uint32_t, f);
    return (u16)((i + 0x7FFFu + ((i >> 16) & 1u)) >> 16);   // RNE
}
// v_cvt_pk_bf16_f32: packs (a,b) -> u32 [b_bf16 | a_bf16] (a in low 16), RNE
__device__ __forceinline__ unsigned pk_bf16(float a, float b) {
    unsigned r;
    asm("v_cvt_pk_bf16_f32 %0, %1, %2" : "=v"(r) : "v"(a), "v"(b));
    return r;
}
// v_permlane32_swap_b32: a' = {a.lo32lanes, b.lo32lanes}, b' = {a.hi, b.hi}
__device__ __forceinline__ void pl32_swap(unsigned &a, unsigned &b) {
    asm volatile("v_permlane32_swap_b32 %0, %1" : "+v"(a), "+v"(b));
}
// direct global->LDS, 16B per lane; LDS dest = wave-uniform base + lane*16
__device__ __forceinline__ void gl_lds16(const u16* g, u16* l) {
    __builtin_amdgcn_global_load_lds((const __attribute__((address_space(1))) void*)g,
                                     (__attribute__((address_space(3))) void*)l,
                                     16, 0, 0);
}

// ---------------------------------------------------------------- cvt f32->bf16 (fallback path)
__global__ __launch_bounds__(256) void cvt_f32_bf16(const float* __restrict__ src,
                                                    u16* __restrict__ dst, int n) {
    int i = (blockIdx.x * 256 + threadIdx.x) * 4;
    int stride = gridDim.x * 256 * 4;
    for (; i < n; i += stride) {
        float4 v = *(const float4*)(src + i);
        u16x4 o;
        o.x = f2bf(v.x); o.y = f2bf(v.y); o.z = f2bf(v.z); o.w = f2bf(v.w);
        *(u16x4*)(dst + i) = o;
    }
}

// ---------------------------------------------------------------- q/k/v cvt, one launch
__global__ __launch_bounds__(256) void cvt3(const float* __restrict__ q,
                                            const float* __restrict__ k,
                                            const float* __restrict__ v,
                                            u16* __restrict__ qb,
                                            u16* __restrict__ kb,
                                            u16* __restrict__ vb) {
    const float* s = blockIdx.y == 0 ? q : blockIdx.y == 1 ? k : v;
    u16* d = blockIdx.y == 0 ? qb : blockIdx.y == 1 ? kb : vb;
    int i = (blockIdx.x * 256 + threadIdx.x) * 8;      // grid.x=4096 covers 8M elems
    float4 a = *(const float4*)(s + i);
    float4 b = *(const float4*)(s + i + 4);
    u32x4 w = {pk_bf16(a.x, a.y), pk_bf16(a.z, a.w), pk_bf16(b.x, b.y), pk_bf16(b.z, b.w)};
    *(u16x8*)(d + i) = __builtin_bit_cast(u16x8, w);
}

// ---------------------------------------------------------------- weight cvt (4 tensors, one launch)
__global__ __launch_bounds__(256) void cvt_w4(const float* __restrict__ s0,
                                              const float* __restrict__ s1,
                                              const float* __restrict__ s2,
                                              const float* __restrict__ s3,
                                              u16* __restrict__ dst) {
    const float* s = blockIdx.y == 0 ? s0 : blockIdx.y == 1 ? s1 : blockIdx.y == 2 ? s2 : s3;
    u16* d = dst + (size_t)blockIdx.y * (DIM_ * DIM_);
    int i = (blockIdx.x * 256 + threadIdx.x) * 8;          // grid.x=512 covers 1M elems
    float4 a = *(const float4*)(s + i);
    float4 b = *(const float4*)(s + i + 4);
    u32x4 w = {pk_bf16(a.x, a.y), pk_bf16(a.z, a.w), pk_bf16(b.x, b.y), pk_bf16(b.z, b.w)};
    *(u16x8*)(d + i) = __builtin_bit_cast(u16x8, w);
}

// ---------------------------------------------------------------- gate permute
// tP[b][it][q][hl][j] = trans[b][q][64*it + 32*(j>>4) + 8*((j>>2)&3) + 4*hl + (j&3)]
// -> attn reads 8 contiguous f32x4 per lane per tile (immediate-offset loads).
__global__ __launch_bounds__(256) void gate_permute(const float* __restrict__ trans,
                                                    float* __restrict__ tP) {
    __shared__ float T[64][68];                       // row stride 272B (16B-aligned)
    const int it = blockIdx.x, qc = blockIdx.y, b = blockIdx.z;
    const float* ib = trans + (size_t)b * N_ * N_;
    const int q0 = qc * 64;
    const int lr = threadIdx.x >> 4, lc = threadIdx.x & 15;
    #pragma unroll
    for (int i = 0; i < 4; i++) {
        int row = i * 16 + lr;
        f32x4 v = *(const f32x4*)(ib + (size_t)(q0 + row) * N_ + it * 64 + lc * 4);
        *(f32x4*)(&T[row][lc * 4]) = v;
    }
    __syncthreads();
    const int q = threadIdx.x >> 2, hl = (threadIdx.x >> 1) & 1, half = threadIdx.x & 1;
    float* ob = tP + ((((size_t)(b * 32 + it)) * 2048 + q0 + q) * 2 + hl) * 32 + half * 16;
    #pragma unroll
    for (int jj = 0; jj < 4; jj++) {
        int j0 = half * 16 + jj * 4;
        int ni = j0 >> 4, r2 = (j0 >> 2) & 3;
        *(f32x4*)(ob + jj * 4) = *(const f32x4*)(&T[q][32 * ni + 8 * r2 + 4 * hl]);
    }
}

// ---------------------------------------------------------------- GEMM C = A @ Bt^T  (R3 + T1, R7-proven)
// A [M,K] bf16 row-major; Bt [NN,K] bf16 row-major; both gl_lds staged (pre-swizzled source).
// MODE 0: bf16 head-split [B,H,N,HD]*scale ; MODE 1: bf16 transposed [B,H,HD,N]*scale ;
// MODE 2: f32 [M,NN] + bias.  XCD-chunked block swizzle (nwg=512, 512%8==0).
template <int MODE>
__global__ __launch_bounds__(256) void gemm_bt(const u16* __restrict__ A,
                                               const u16* __restrict__ Bt,
                                               void* __restrict__ Cout,
                                               const float* __restrict__ bias,
                                               float scale, int M, int NN, int K) {
    __shared__ __align__(16) u16 lga[128 * 64];
    __shared__ __align__(16) u16 lgb[128 * 64];
    const int tid  = threadIdx.x;
    const int lane = tid & 63, wave = tid >> 6;
    const int wm = wave >> 1, wn = wave & 1;
    // T1: XCD i executes a contiguous run of 64 work items (8 A-panels + whole B in its L2)
    int lin = blockIdx.x + gridDim.x * blockIdx.y;
    int w   = (lin & 7) * 64 + (lin >> 3);
    const int row0 = (w >> 3) * 128, col0 = (w & 7) * 128;

    f32x4 acc[4][4] = {};

    auto stageLds = [&](const u16* G, u16* L, int rowbase, int k0) {
        #pragma unroll
        for (int i = 0; i < 4; i++) {
            int rb = wave * 32 + i * 8;
            int r  = rb + (lane >> 3);
            int cc = (lane & 7) ^ (lane >> 3);
            gl_lds16(G + (size_t)(rowbase + r) * K + k0 + cc * 8, L + rb * 64);
        }
    };

    for (int k0 = 0; k0 < K; k0 += 64) {
        stageLds(A,  lga, row0, k0);
        stageLds(Bt, lgb, col0, k0);
        __syncthreads();
        #pragma unroll
        for (int kk = 0; kk < 2; kk++) {
            s16x8 af[4], bfr[4];
            #pragma unroll
            for (int mi = 0; mi < 4; mi++) {
                int r = wm * 64 + mi * 16 + (lane & 15);
                int sc = (kk * 4 + (lane >> 4)) ^ (lane & 7);
                af[mi] = *(const s16x8*)(&lga[r * 64 + sc * 8]);
            }
            #pragma unroll
            for (int ni = 0; ni < 4; ni++) {
                int r = wn * 64 + ni * 16 + (lane & 15);
                int sc = (kk * 4 + (lane >> 4)) ^ (lane & 7);
                bfr[ni] = *(const s16x8*)(&lgb[r * 64 + sc * 8]);
            }
            #pragma unroll
            for (int mi = 0; mi < 4; mi++)
                #pragma unroll
                for (int ni = 0; ni < 4; ni++)
                    acc[mi][ni] = __builtin_amdgcn_mfma_f32_16x16x32_bf16(
                        af[mi], bfr[ni], acc[mi][ni], 0, 0, 0);
        }
        __syncthreads();
    }

    #pragma unroll
    for (int mi = 0; mi < 4; mi++) {
        #pragma unroll
        for (int ni = 0; ni < 4; ni++) {
            #pragma unroll
            for (int r = 0; r < 4; r++) {
                int grow = row0 + wm * 64 + mi * 16 + ((lane >> 4) << 2) + r;
                int gcol = col0 + wn * 64 + ni * 16 + (lane & 15);
                float vv = acc[mi][ni][r];
                if (MODE == 2) {
                    ((float*)Cout)[(size_t)grow * NN + gcol] = vv + bias[gcol];
                } else {
                    vv *= scale;
                    int bb = grow >> 11, n = grow & (N_ - 1);
                    int hh = gcol >> 7,  d = gcol & (HD_ - 1);
                    size_t idx = (MODE == 0)
                        ? ((size_t)(bb * H_ + hh) * N_ + n) * HD_ + d
                        : ((size_t)(bb * H_ + hh) * HD_ + d) * N_ + n;
                    ((u16*)Cout)[idx] = f2bf(vv);
                }
            }
        }
    }
}

// ---------------------------------------------------------------- gated flash attention (no-LDS)
// R6/R8-verified math (32x32 swapped S^T = K·Q^T, lane owns q-row), but K/V fragments are
// read DIRECTLY from global (L2-resident per head: 512KB K + 512KB V, ~2 heads/XCD via
// XCD-chunked grid — m169 precedent: staging L2-fit data is pure overhead). No LDS, no
// barriers, no bank conflicts: waves free-run and self-pipeline tiles.
// Gates come pre-permuted from tP (8 contiguous f32x4 per lane per tile).
__global__ __launch_bounds__(256) void attn_nolds(const u16* __restrict__ Qh,
                                                  const u16* __restrict__ Kh,
                                                  const u16* __restrict__ Vt,
                                                  const float* __restrict__ tP,
                                                  u16* __restrict__ xout) {
    const int lane = threadIdx.x & 63, wave = threadIdx.x >> 6;
    const int lq = lane & 31, hl = lane >> 5;

    // XCD chunking: each XCD gets 64 consecutive work items (one b, 4 heads)
    int lin = blockIdx.x + 16 * (blockIdx.y + 8 * blockIdx.z);
    int nl  = (lin & 7) * 64 + (lin >> 3);
    const int qt = nl & 15, hh = (nl >> 4) & 7, b = nl >> 7;
    const int q0 = qt * 128 + wave * 32;
    const int q  = q0 + lq;                         // this lane's q row

    const u16* Qbh = Qh + (size_t)(b * H_ + hh) * N_ * HD_;
    // per-lane fragment bases (16B chunks; row selected by lq, dword-half by hl)
    const u16* Kl = Kh + (size_t)(b * H_ + hh) * N_ * HD_ + (size_t)lq * HD_ + hl * 8;
    const u16* Vl = Vt + (size_t)(b * H_ + hh) * HD_ * N_ + (size_t)lq * N_ + hl * 8;
    const float* tPl = tP + (((size_t)b * 32 * 2048 + q) * 2 + hl) * 32;

    // Q fragments (B-operand): qf[s] = Q[q][s*16 + hl*8 + j]
    s16x8 qf[8];
    #pragma unroll
    for (int s = 0; s < 8; s++)
        qf[s] = *(const s16x8*)(Qbh + (size_t)q * HD_ + s * 16 + hl * 8);

    float m = -3.0e38f, l = 0.f;
    f32x16 aoT[4] = {};    // O^T[d=(reg&3)+8*(reg>>2)+4*hl+32*dt][q=lq]

    for (int it = 0; it < N_ / 64; it++) {
        const int kv0 = it * 64;

        // gate values: 8 contiguous f32x4 from tP (immediate offsets from one base)
        f32x4 ttv[8];
        #pragma unroll
        for (int jj = 0; jj < 8; jj++)
            ttv[jj] = *(const f32x4*)(tPl + (size_t)it * (2048 * 64) + jj * 4);

        // S^T = K · Q^T  (A-frag direct from global; K tile lines L1/L2-hot across s)
        const u16* Kt = Kl + (size_t)kv0 * HD_;
        f32x16 sT[2] = {};
        __builtin_amdgcn_s_setprio(1);
        #pragma unroll
        for (int s = 0; s < 8; s++)
            #pragma unroll
            for (int ni = 0; ni < 2; ni++) {
                s16x8 kf = *(const s16x8*)(Kt + ni * (32 * HD_) + s * 16);
                sT[ni] = __builtin_amdgcn_mfma_f32_32x32x16_bf16(kf, qf[s], sT[ni], 0, 0, 0);
            }
        __builtin_amdgcn_s_setprio(0);

        // gate + lane-local row max (one cross-half exchange)
        float mx = -3.0e38f;
        #pragma unroll
        for (int ni = 0; ni < 2; ni++)
            #pragma unroll
            for (int idx = 0; idx < 16; idx++) {
                float g = sT[ni][idx] * ttv[(ni << 2) | (idx >> 2)][idx & 3];
                sT[ni][idx] = g;
                mx = fmaxf(mx, g);
            }
        mx = fmaxf(mx, __shfl_xor(mx, 32));

        // defer-rescale (T13)
        if (__any(mx > m + 8.0f)) {
            float mn = fmaxf(m, mx);
            float sfv = __builtin_amdgcn_exp2f(m - mn);
            m = mn;
            l *= sfv;
            #pragma unroll
            for (int dt = 0; dt < 4; dt++)
                #pragma unroll
                for (int e = 0; e < 16; e++) aoT[dt][e] *= sfv;
        }

        // P = exp2(g - m); denom includes ALL entries; PV term zeroed where g==0
        float rs = 0.f;
        #pragma unroll
        for (int ni = 0; ni < 2; ni++)
            #pragma unroll
            for (int e = 0; e < 16; e++) {
                float g = sT[ni][e];
                float p = __builtin_amdgcn_exp2f(g - m);
                rs += p;
                sT[ni][e] = (g != 0.0f) ? p : 0.0f;
            }
        rs += __shfl_xor(rs, 32);
        l += rs;

        // pack P -> A-frags: 16 cvt_pk + 8 permlane32_swap (R4-verified)
        s16x8 pfrag[4];
        #pragma unroll
        for (int sp = 0; sp < 4; sp++) {
            const int ni = sp >> 1;
            const int ru = (2 * sp) & 3, rv2 = (2 * sp + 1) & 3;
            unsigned u0 = pk_bf16(sT[ni][ru * 4 + 0], sT[ni][ru * 4 + 1]);
            unsigned u1 = pk_bf16(sT[ni][ru * 4 + 2], sT[ni][ru * 4 + 3]);
            unsigned v0 = pk_bf16(sT[ni][rv2 * 4 + 0], sT[ni][rv2 * 4 + 1]);
            unsigned v1 = pk_bf16(sT[ni][rv2 * 4 + 2], sT[ni][rv2 * 4 + 3]);
            pl32_swap(u0, v0);
            pl32_swap(u1, v1);
            u32x4 w = {u0, u1, v0, v1};
            pfrag[sp] = __builtin_bit_cast(s16x8, w);
        }

        // O^T += V^T · P^T  (A-frag direct from global; V tile lines L1/L2-hot across sp)
        const u16* Vtile = Vl + kv0;
        __builtin_amdgcn_s_setprio(1);
        #pragma unroll
        for (int dt = 0; dt < 4; dt++)
            #pragma unroll
            for (int sp = 0; sp < 4; sp++) {
                s16x8 vf = *(const s16x8*)(Vtile + (size_t)dt * (32 * N_) + sp * 16);
                aoT[dt] = __builtin_amdgcn_mfma_f32_32x32x16_bf16(vf, pfrag[sp], aoT[dt], 0, 0, 0);
            }
        __builtin_amdgcn_s_setprio(0);
    }

    // normalize and write x[b, n=q, hh*HD + d]; d = (reg&3) + 8*(reg>>2) + 4*hl + 32*dt
    float inv = 1.0f / l;
    u16* orow = xout + ((size_t)(b * N_ + q)) * DIM_ + hh * HD_;
    #pragma unroll
    for (int dt = 0; dt < 4; dt++)
        #pragma unroll
        for (int r2 = 0; r2 < 4; r2++) {
            u16x4 ov;
            #pragma unroll
            for (int e = 0; e < 4; e++)
                ov[e] = f2bf(aoT[dt][r2 * 4 + e] * inv);
            *(u16x4*)(orow + dt * 32 + r2 * 8 + hl * 4) = ov;
        }
}

// ---------------------------------------------------------------- R3 fallback attention
// (used only if ws_size can't hold tP; proven at 155.7 us)
__global__ __launch_bounds__(512) void attn_fb(const u16* __restrict__ Qh,
                                               const u16* __restrict__ Kh,
                                               const u16* __restrict__ Vt,
                                               const float* __restrict__ trans,
                                               u16* __restrict__ xout) {
    __shared__ __align__(16) u16 kt[64 * 128];
    __shared__ __align__(16) u16 vt[128 * 64];
    __shared__ __align__(16) u16 plds[8][16 * 72];

    const int tid = threadIdx.x, lane = tid & 63, wave = tid >> 6;
    const int qt = blockIdx.x, h = blockIdx.y, b = blockIdx.z;
    const int qrow_base = qt * 128 + wave * 16;

    const u16* Qbh = Qh + (size_t)(b * H_ + h) * N_ * HD_;
    const u16* Kbh = Kh + (size_t)(b * H_ + h) * N_ * HD_;
    const u16* Vbh = Vt + (size_t)(b * H_ + h) * HD_ * N_;
    const float* trow = trans + (size_t)b * N_ * N_
                      + (size_t)(qrow_base + ((lane >> 4) << 2)) * N_ + (lane & 15);

    s16x8 qf[4];
    {
        int r = qrow_base + (lane & 15);
        #pragma unroll
        for (int kd = 0; kd < 4; kd++)
            qf[kd] = *(const s16x8*)(Qbh + (size_t)r * HD_ + kd * 32 + ((lane >> 4) << 3));
    }
    auto stageKV = [&](int kv0) {
        int rbk = wave * 8, rbv = wave * 16;
        #pragma unroll
        for (int j = 0; j < 2; j++) {
            int c = j * 64 + lane;
            int rk = rbk + (c >> 4), ck = (c & 15) ^ (rk & 15);
            gl_lds16(Kbh + (size_t)(kv0 + rk) * HD_ + ck * 8, kt + rbk * 128 + j * 512);
            int rv = rbv + (c >> 3), cv = (c & 7) ^ (rv & 7);
            gl_lds16(Vbh + (size_t)rv * N_ + kv0 + cv * 8, vt + rbv * 64 + j * 512);
        }
    };

    float m[4], l[4];
    #pragma unroll
    for (int r = 0; r < 4; r++) { m[r] = -3.0e38f; l[r] = 0.f; }
    f32x4 ao[8] = {};

    for (int kv0 = 0; kv0 < N_; kv0 += 64) {
        stageKV(kv0);
        __syncthreads();
        f32x4 s[4] = {};
        #pragma unroll
        for (int kd = 0; kd < 4; kd++)
            #pragma unroll
            for (int ni = 0; ni < 4; ni++) {
                int r = ni * 16 + (lane & 15);
                int sc = (kd * 4 + (lane >> 4)) ^ (lane & 15);
                s16x8 bfr = *(const s16x8*)(&kt[r * 128 + sc * 8]);
                s[ni] = __builtin_amdgcn_mfma_f32_16x16x32_bf16(qf[kd], bfr, s[ni], 0, 0, 0);
            }
        float pmax[4] = {-3.0e38f, -3.0e38f, -3.0e38f, -3.0e38f};
        #pragma unroll
        for (int ni = 0; ni < 4; ni++)
            #pragma unroll
            for (int r = 0; r < 4; r++) {
                float tt = trow[(size_t)r * N_ + kv0 + ni * 16];
                float gg = s[ni][r] * tt;
                s[ni][r] = gg;
                pmax[r] = fmaxf(pmax[r], gg);
            }
        #pragma unroll
        for (int r = 0; r < 4; r++) {
            float p = pmax[r];
            p = fmaxf(p, __shfl_xor(p, 1));
            p = fmaxf(p, __shfl_xor(p, 2));
            p = fmaxf(p, __shfl_xor(p, 4));
            p = fmaxf(p, __shfl_xor(p, 8));
            pmax[r] = p;
        }
        bool need = false;
        #pragma unroll
        for (int r = 0; r < 4; r++) need = need || (pmax[r] > m[r] + 8.0f);
        if (__any(need)) {
            #pragma unroll
            for (int r = 0; r < 4; r++) {
                float mn = fmaxf(m[r], pmax[r]);
                float sfv = __builtin_amdgcn_exp2f(m[r] - mn);
                m[r] = mn; l[r] *= sfv;
                #pragma unroll
                for (int t = 0; t < 8; t++) ao[t][r] *= sfv;
            }
        }
        float rowsum[4] = {0.f, 0.f, 0.f, 0.f};
        u16* pw = &plds[wave][0];
        #pragma unroll
        for (int ni = 0; ni < 4; ni++)
            #pragma unroll
            for (int r = 0; r < 4; r++) {
                float gg = s[ni][r];
                float e = __builtin_amdgcn_exp2f(gg - m[r]);
                rowsum[r] += e;
                float pe = (gg != 0.0f) ? e : 0.0f;
                pw[(((lane >> 4) << 2) + r) * 72 + ni * 16 + (lane & 15)] = f2bf(pe);
            }
        #pragma unroll
        for (int r = 0; r < 4; r++) {
            float ssum = rowsum[r];
            ssum += __shfl_xor(ssum, 1);
            ssum += __shfl_xor(ssum, 2);
            ssum += __shfl_xor(ssum, 4);
            ssum += __shfl_xor(ssum, 8);
            l[r] += ssum;
        }
        #pragma unroll
        for (int kk = 0; kk < 2; kk++) {
            s16x8 pa = *(const s16x8*)(&pw[(lane & 15) * 72 + kk * 32 + ((lane >> 4) << 3)]);
            #pragma unroll
            for (int t = 0; t < 8; t++) {
                int r = t * 16 + (lane & 15);
                int sc = (kk * 4 + (lane >> 4)) ^ (r & 7);
                s16x8 vb = *(const s16x8*)(&vt[r * 64 + sc * 8]);
                ao[t] = __builtin_amdgcn_mfma_f32_16x16x32_bf16(pa, vb, ao[t], 0, 0, 0);
            }
        }
        __syncthreads();
    }
    #pragma unroll
    for (int r = 0; r < 4; r++) {
        float inv = 1.0f / l[r];
        int n = qrow_base + ((lane >> 4) << 2) + r;
        u16* orow = xout + ((size_t)(b * N_ + n)) * DIM_ + h * HD_;
        #pragma unroll
        for (int t = 0; t < 8; t++)
            orow[t * 16 + (lane & 15)] = f2bf(ao[t][r] * inv);
    }
}

// ---------------------------------------------------------------- launch
extern "C" void kernel_launch(void* const* d_in, const int* in_sizes, int n_in,
                              void* d_out, int out_size, void* d_ws, size_t ws_size,
                              hipStream_t stream) {
    const float* q     = (const float*)d_in[0];
    const float* k     = (const float*)d_in[1];
    const float* v     = (const float*)d_in[2];
    const float* trans = (const float*)d_in[3];
    const float* Wq    = (const float*)d_in[4];
    const float* Wk    = (const float*)d_in[5];
    const float* Wv    = (const float*)d_in[6];
    const float* Wp    = (const float*)d_in[7];
    const float* bp    = (const float*)d_in[8];

    // workspace map (big path, 136 MiB):
    //  [0,16M): xb attention output bf16
    //  [16M..24M): Wq,Wk,Wv,Wp bf16 ; [24..40M): Qh ; [40..56M): Kh ; [56..72M): Vt
    //  [72M..120M): qb/kb/vb bf16 (dead after projections)
    //  [72M..136M): tP permuted gates (written after qb/kb/vb are dead)
    char* ws = (char*)d_ws;
    u16* xb  = (u16*)(ws);
    u16* wqb = (u16*)(ws + (16u << 20));
    u16* wkb = (u16*)(ws + (18u << 20));
    u16* wvb = (u16*)(ws + (20u << 20));
    u16* wpb = (u16*)(ws + (22u << 20));
    u16* QhB = (u16*)(ws + (24u << 20));
    u16* KhB = (u16*)(ws + (40u << 20));
    u16* VtB = (u16*)(ws + (56u << 20));
    u16* qb  = (u16*)(ws + (72u << 20));
    u16* kb  = (u16*)(ws + (88u << 20));
    u16* vb  = (u16*)(ws + (104u << 20));
    float* tP = (float*)(ws + (72u << 20));
    const bool big = ws_size >= (136ull << 20);

    dim3 blk(256);
    cvt_w4<<<dim3(512, 4), blk, 0, stream>>>(Wq, Wk, Wv, Wp, wqb);

    dim3 pg(DIM_ / 128, MTOK / 128);   // (8, 64)

    if (big) {
        cvt3<<<dim3(4096, 3), blk, 0, stream>>>(q, k, v, qb, kb, vb);
        gemm_bt<0><<<pg, blk, 0, stream>>>(qb, wqb, QhB, nullptr, QSCALE_, MTOK, DIM_, DIM_);
        gemm_bt<0><<<pg, blk, 0, stream>>>(kb, wkb, KhB, nullptr, 1.0f, MTOK, DIM_, DIM_);
        gemm_bt<1><<<pg, blk, 0, stream>>>(vb, wvb, VtB, nullptr, 1.0f, MTOK, DIM_, DIM_);
        gate_permute<<<dim3(32, 32, B_), blk, 0, stream>>>(trans, tP);
        attn_nolds<<<dim3(16, 8, 4), blk, 0, stream>>>(QhB, KhB, VtB, tP, xb);
    } else {
        u16* tmp = xb;   // serial staging, reused as x afterwards
        cvt_f32_bf16<<<dim3(8192), blk, 0, stream>>>(q, tmp, MTOK * DIM_);
        gemm_bt<0><<<pg, blk, 0, stream>>>(tmp, wqb, QhB, nullptr, QSCALE_, MTOK, DIM_, DIM_);
        cvt_f32_bf16<<<dim3(8192), blk, 0, stream>>>(k, tmp, MTOK * DIM_);
        gemm_bt<0><<<pg, blk, 0, stream>>>(tmp, wkb, KhB, nullptr, 1.0f, MTOK, DIM_, DIM_);
        cvt_f32_bf16<<<dim3(8192), blk, 0, stream>>>(v, tmp, MTOK * DIM_);
        gemm_bt<1><<<pg, blk, 0, stream>>>(tmp, wvb, VtB, nullptr, 1.0f, MTOK, DIM_, DIM_);
        attn_fb<<<dim3(N_ / 128, H_, B_), dim3(512), 0, stream>>>(QhB, KhB, VtB, trans, xb);
    }

    gemm_bt<2><<<pg, blk, 0, stream>>>(xb, wpb, d_out, bp, 1.0f, MTOK, DIM_, DIM_);
}

// Round 11
// 274.749 us; speedup vs baseline: 1.8571x; 1.8571x over previous
//
#include <hip/hip_runtime.h>
#include <hip/hip_bf16.h>
#include <stdint.h>

// Problem constants (fixed by the reference)
#define B_    4
#define N_    2048
#define DIM_  1024
#define H_    8
#define HD_   128
#define MTOK  (B_ * N_)          // 8192 tokens
#define SCALE_  0.08838834764831845f   // HD^-0.5
#define LOG2E_  1.4426950408889634f
#define QSCALE_ (SCALE_ * LOG2E_)      // folded into Q projection epilogue

typedef unsigned short u16;
typedef __attribute__((ext_vector_type(4)))  float f32x4;
typedef __attribute__((ext_vector_type(16))) float f32x16;
typedef __attribute__((ext_vector_type(8)))  short s16x8;   // 8 bf16 — MFMA A/B frag
typedef __attribute__((ext_vector_type(8)))  u16  u16x8;
typedef __attribute__((ext_vector_type(4)))  u16  u16x4;
typedef __attribute__((ext_vector_type(4)))  unsigned u32x4;

__device__ __forceinline__ u16 f2bf(float f) {
    uint32_t i = __builtin_bit_cast(uint32_t, f);
    return (u16)((i + 0x7FFFu + ((i >> 16) & 1u)) >> 16);   // RNE
}
__device__ __forceinline__ unsigned pk_bf16(float a, float b) {
    unsigned r;
    asm("v_cvt_pk_bf16_f32 %0, %1, %2" : "=v"(r) : "v"(a), "v"(b));
    return r;
}
__device__ __forceinline__ void pl32_swap(unsigned &a, unsigned &b) {
    asm volatile("v_permlane32_swap_b32 %0, %1" : "+v"(a), "+v"(b));
}
__device__ __forceinline__ void gl_lds16(const u16* g, u16* l) {
    __builtin_amdgcn_global_load_lds((const __attribute__((address_space(1))) void*)g,
                                     (__attribute__((address_space(3))) void*)l,
                                     16, 0, 0);
}

// ---------------------------------------------------------------- q/k/v cvt, one launch
__global__ __launch_bounds__(256) void cvt3(const float* __restrict__ q,
                                            const float* __restrict__ k,
                                            const float* __restrict__ v,
                                            u16* __restrict__ qb) {
    const float* s = blockIdx.y == 0 ? q : blockIdx.y == 1 ? k : v;
    u16* d = qb + (size_t)blockIdx.y * (8u << 20);     // qb/kb/vb stride 16 MiB
    int i = (blockIdx.x * 256 + threadIdx.x) * 8;      // grid.x=4096 covers 8M elems
    float4 a = *(const float4*)(s + i);
    float4 b = *(const float4*)(s + i + 4);
    u32x4 w = {pk_bf16(a.x, a.y), pk_bf16(a.z, a.w), pk_bf16(b.x, b.y), pk_bf16(b.z, b.w)};
    *(u16x8*)(d + i) = __builtin_bit_cast(u16x8, w);
}

// ---------------------------------------------------------------- weight cvt (4 tensors, one launch)
__global__ __launch_bounds__(256) void cvt_w4(const float* __restrict__ s0,
                                              const float* __restrict__ s1,
                                              const float* __restrict__ s2,
                                              const float* __restrict__ s3,
                                              u16* __restrict__ dst) {
    const float* s = blockIdx.y == 0 ? s0 : blockIdx.y == 1 ? s1 : blockIdx.y == 2 ? s2 : s3;
    u16* d = dst + (size_t)blockIdx.y * (DIM_ * DIM_);
    int i = (blockIdx.x * 256 + threadIdx.x) * 8;          // grid.x=512 covers 1M elems
    float4 a = *(const float4*)(s + i);
    float4 b = *(const float4*)(s + i + 4);
    u32x4 w = {pk_bf16(a.x, a.y), pk_bf16(a.z, a.w), pk_bf16(b.x, b.y), pk_bf16(b.z, b.w)};
    *(u16x8*)(d + i) = __builtin_bit_cast(u16x8, w);
}

// ---------------------------------------------------------------- gate permute (R9-verified mapping)
// tP[b][it][q][hl][j] = trans[b][q][64*it + 32*(j>>4) + 8*((j>>2)&3) + 4*hl + (j&3)]
__global__ __launch_bounds__(256) void gate_permute(const float* __restrict__ trans,
                                                    float* __restrict__ tP) {
    __shared__ float T[64][68];
    const int it = blockIdx.x, qc = blockIdx.y, b = blockIdx.z;
    const float* ib = trans + (size_t)b * N_ * N_;
    const int q0 = qc * 64;
    const int lr = threadIdx.x >> 4, lc = threadIdx.x & 15;
    #pragma unroll
    for (int i = 0; i < 4; i++) {
        int row = i * 16 + lr;
        f32x4 v = *(const f32x4*)(ib + (size_t)(q0 + row) * N_ + it * 64 + lc * 4);
        *(f32x4*)(&T[row][lc * 4]) = v;
    }
    __syncthreads();
    const int q = threadIdx.x >> 2, hl = (threadIdx.x >> 1) & 1, half = threadIdx.x & 1;
    float* ob = tP + ((((size_t)(b * 32 + it)) * 2048 + q0 + q) * 2 + hl) * 32 + half * 16;
    #pragma unroll
    for (int jj = 0; jj < 4; jj++) {
        int j0 = half * 16 + jj * 4;
        int ni = j0 >> 4, r2 = (j0 >> 2) & 3;
        *(f32x4*)(ob + jj * 4) = *(const f32x4*)(&T[q][32 * ni + 8 * r2 + 4 * hl]);
    }
}

// ---------------------------------------------------------------- fused QKV projection GEMM
// z selects (A, Bt, Cout, scale, epilogue): z<2 -> head-split [B,H,N,HD] (Q,K);
// z==2 -> transposed [B,H,HD,N] (V).  A/C stride 8M u16; Bt stride 1M u16.
__global__ __launch_bounds__(256) void gemm_qkv(const u16* __restrict__ Abase,
                                                const u16* __restrict__ Wbase,
                                                u16* __restrict__ Cbase) {
    __shared__ __align__(16) u16 lga[128 * 64];
    __shared__ __align__(16) u16 lgb[128 * 64];
    const int tid  = threadIdx.x;
    const int lane = tid & 63, wave = tid >> 6;
    const int wm = wave >> 1, wn = wave & 1;
    const int z = blockIdx.z;
    const u16* A  = Abase + (size_t)z * (8u << 20);
    const u16* Bt = Wbase + (size_t)z * (DIM_ * DIM_);
    u16* Cout     = Cbase + (size_t)z * (8u << 20);
    const float scale = (z == 0) ? QSCALE_ : 1.0f;
    int lin = blockIdx.x + gridDim.x * blockIdx.y;
    int w   = (lin & 7) * 64 + (lin >> 3);
    const int row0 = (w >> 3) * 128, col0 = (w & 7) * 128;

    f32x4 acc[4][4] = {};

    auto stageLds = [&](const u16* G, u16* L, int rowbase, int k0) {
        #pragma unroll
        for (int i = 0; i < 4; i++) {
            int rb = wave * 32 + i * 8;
            int r  = rb + (lane >> 3);
            int cc = (lane & 7) ^ (lane >> 3);
            gl_lds16(G + (size_t)(rowbase + r) * DIM_ + k0 + cc * 8, L + rb * 64);
        }
    };

    for (int k0 = 0; k0 < DIM_; k0 += 64) {
        stageLds(A,  lga, row0, k0);
        stageLds(Bt, lgb, col0, k0);
        __syncthreads();
        #pragma unroll
        for (int kk = 0; kk < 2; kk++) {
            s16x8 af[4], bfr[4];
            #pragma unroll
            for (int mi = 0; mi < 4; mi++) {
                int r = wm * 64 + mi * 16 + (lane & 15);
                int sc = (kk * 4 + (lane >> 4)) ^ (lane & 7);
                af[mi] = *(const s16x8*)(&lga[r * 64 + sc * 8]);
            }
            #pragma unroll
            for (int ni = 0; ni < 4; ni++) {
                int r = wn * 64 + ni * 16 + (lane & 15);
                int sc = (kk * 4 + (lane >> 4)) ^ (lane & 7);
                bfr[ni] = *(const s16x8*)(&lgb[r * 64 + sc * 8]);
            }
            #pragma unroll
            for (int mi = 0; mi < 4; mi++)
                #pragma unroll
                for (int ni = 0; ni < 4; ni++)
                    acc[mi][ni] = __builtin_amdgcn_mfma_f32_16x16x32_bf16(
                        af[mi], bfr[ni], acc[mi][ni], 0, 0, 0);
        }
        __syncthreads();
    }

    #pragma unroll
    for (int mi = 0; mi < 4; mi++) {
        #pragma unroll
        for (int ni = 0; ni < 4; ni++) {
            #pragma unroll
            for (int r = 0; r < 4; r++) {
                int grow = row0 + wm * 64 + mi * 16 + ((lane >> 4) << 2) + r;
                int gcol = col0 + wn * 64 + ni * 16 + (lane & 15);
                float vv = acc[mi][ni][r] * scale;
                int bb = grow >> 11, n = grow & (N_ - 1);
                int hh = gcol >> 7,  d = gcol & (HD_ - 1);
                size_t idx = (z < 2)
                    ? ((size_t)(bb * H_ + hh) * N_ + n) * HD_ + d
                    : ((size_t)(bb * H_ + hh) * HD_ + d) * N_ + n;
                Cout[idx] = f2bf(vv);
            }
        }
    }
}

// ---------------------------------------------------------------- output projection GEMM
__global__ __launch_bounds__(256) void gemm_out(const u16* __restrict__ A,
                                                const u16* __restrict__ Bt,
                                                float* __restrict__ Cout,
                                                const float* __restrict__ bias) {
    __shared__ __align__(16) u16 lga[128 * 64];
    __shared__ __align__(16) u16 lgb[128 * 64];
    const int tid  = threadIdx.x;
    const int lane = tid & 63, wave = tid >> 6;
    const int wm = wave >> 1, wn = wave & 1;
    int lin = blockIdx.x + gridDim.x * blockIdx.y;
    int w   = (lin & 7) * 64 + (lin >> 3);
    const int row0 = (w >> 3) * 128, col0 = (w & 7) * 128;

    f32x4 acc[4][4] = {};

    auto stageLds = [&](const u16* G, u16* L, int rowbase, int k0) {
        #pragma unroll
        for (int i = 0; i < 4; i++) {
            int rb = wave * 32 + i * 8;
            int r  = rb + (lane >> 3);
            int cc = (lane & 7) ^ (lane >> 3);
            gl_lds16(G + (size_t)(rowbase + r) * DIM_ + k0 + cc * 8, L + rb * 64);
        }
    };

    for (int k0 = 0; k0 < DIM_; k0 += 64) {
        stageLds(A,  lga, row0, k0);
        stageLds(Bt, lgb, col0, k0);
        __syncthreads();
        #pragma unroll
        for (int kk = 0; kk < 2; kk++) {
            s16x8 af[4], bfr[4];
            #pragma unroll
            for (int mi = 0; mi < 4; mi++) {
                int r = wm * 64 + mi * 16 + (lane & 15);
                int sc = (kk * 4 + (lane >> 4)) ^ (lane & 7);
                af[mi] = *(const s16x8*)(&lga[r * 64 + sc * 8]);
            }
            #pragma unroll
            for (int ni = 0; ni < 4; ni++) {
                int r = wn * 64 + ni * 16 + (lane & 15);
                int sc = (kk * 4 + (lane >> 4)) ^ (lane & 7);
                bfr[ni] = *(const s16x8*)(&lgb[r * 64 + sc * 8]);
            }
            #pragma unroll
            for (int mi = 0; mi < 4; mi++)
                #pragma unroll
                for (int ni = 0; ni < 4; ni++)
                    acc[mi][ni] = __builtin_amdgcn_mfma_f32_16x16x32_bf16(
                        af[mi], bfr[ni], acc[mi][ni], 0, 0, 0);
        }
        __syncthreads();
    }

    #pragma unroll
    for (int mi = 0; mi < 4; mi++) {
        #pragma unroll
        for (int ni = 0; ni < 4; ni++) {
            #pragma unroll
            for (int r = 0; r < 4; r++) {
                int grow = row0 + wm * 64 + mi * 16 + ((lane >> 4) << 2) + r;
                int gcol = col0 + wn * 64 + ni * 16 + (lane & 15);
                Cout[(size_t)grow * DIM_ + gcol] = acc[mi][ni][r] + bias[gcol];
            }
        }
    }
}

// ---------------------------------------------------------------- gated flash attention (swapped)
// R8-proven core + tP vectorized gate reads.
__global__ __launch_bounds__(256, 2) void attn_swapped(const u16* __restrict__ Qh,
                                                       const u16* __restrict__ Kh,
                                                       const u16* __restrict__ Vt,
                                                       const float* __restrict__ tP,
                                                       u16* __restrict__ xout) {
    __shared__ __align__(16) u16 kt[2][64 * 128];   // K [kv=64][d=128], slot = c ^ mK(r)
    __shared__ __align__(16) u16 vt[2][128 * 64];   // Vt [d=128][kv=64], slot = c ^ mV(r)

    const int tid = threadIdx.x, lane = tid & 63, wave = tid >> 6;
    const int lq = lane & 31, hl = lane >> 5;

    int lin = blockIdx.x + 16 * (blockIdx.y + 8 * blockIdx.z);
    int nl  = (lin & 7) * 64 + (lin >> 3);
    const int qt = nl & 15, hh = (nl >> 4) & 7, b = nl >> 7;
    const int q0 = qt * 128 + wave * 32;
    const int q  = q0 + lq;

    const u16* Qbh = Qh + (size_t)(b * H_ + hh) * N_ * HD_;
    const u16* Kbh = Kh + (size_t)(b * H_ + hh) * N_ * HD_;
    const u16* Vbh = Vt + (size_t)(b * H_ + hh) * HD_ * N_;
    const float* tPl = tP + (((size_t)b * 32 * 2048 + q) * 2 + hl) * 32;

    s16x8 qf[8];
    #pragma unroll
    for (int s = 0; s < 8; s++)
        qf[s] = *(const s16x8*)(Qbh + (size_t)q * HD_ + s * 16 + hl * 8);

    auto stageKV = [&](int kv0, int bi) {
        #pragma unroll
        for (int i = 0; i < 4; i++) {
            int rk = wave * 16 + i * 4 + (lane >> 4);
            int ck = (lane & 15) ^ (rk & 15) ^ ((rk & 16) >> 2);
            gl_lds16(Kbh + (size_t)(kv0 + rk) * HD_ + ck * 8,
                     &kt[bi][(wave * 16 + i * 4) * 128]);
            int rv = wave * 32 + i * 8 + (lane >> 3);
            int cv = (lane & 7) ^ (rv & 7) ^ ((rv >> 3) & 3);
            gl_lds16(Vbh + (size_t)rv * N_ + kv0 + cv * 8,
                     &vt[bi][(wave * 32 + i * 8) * 64]);
        }
    };

    const int mKl = (lq & 15) ^ ((lq & 16) >> 2);
    const int mVl = (lq & 7) ^ ((lq >> 3) & 3);

    float m = -3.0e38f, l = 0.f;
    f32x16 aoT[4] = {};

    stageKV(0, 0);
    __syncthreads();

    for (int it = 0; it < N_ / 64; it++) {
        const int kv0 = it * 64, cur = it & 1;
        if (it + 1 < N_ / 64) stageKV(kv0 + 64, cur ^ 1);

        f32x4 ttv[8];
        #pragma unroll
        for (int jj = 0; jj < 8; jj++)
            ttv[jj] = *(const f32x4*)(tPl + (size_t)it * (2048 * 64) + jj * 4);

        f32x16 sT[2] = {};
        __builtin_amdgcn_s_setprio(1);
        #pragma unroll
        for (int s = 0; s < 8; s++)
            #pragma unroll
            for (int ni = 0; ni < 2; ni++) {
                int r = ni * 32 + lq;
                int slot = (2 * s + hl) ^ mKl;
                s16x8 kf = *(const s16x8*)(&kt[cur][r * 128 + slot * 8]);
                sT[ni] = __builtin_amdgcn_mfma_f32_32x32x16_bf16(kf, qf[s], sT[ni], 0, 0, 0);
            }
        __builtin_amdgcn_s_setprio(0);

        float mx = -3.0e38f;
        #pragma unroll
        for (int ni = 0; ni < 2; ni++)
            #pragma unroll
            for (int idx = 0; idx < 16; idx++) {
                float g = sT[ni][idx] * ttv[(ni << 2) | (idx >> 2)][idx & 3];
                sT[ni][idx] = g;
                mx = fmaxf(mx, g);
            }
        mx = fmaxf(mx, __shfl_xor(mx, 32));

        if (__any(mx > m + 8.0f)) {
            float mn = fmaxf(m, mx);
            float sfv = __builtin_amdgcn_exp2f(m - mn);
            m = mn;
            l *= sfv;
            #pragma unroll
            for (int dt = 0; dt < 4; dt++)
                #pragma unroll
                for (int e = 0; e < 16; e++) aoT[dt][e] *= sfv;
        }

        float rs = 0.f;
        #pragma unroll
        for (int ni = 0; ni < 2; ni++)
            #pragma unroll
            for (int e = 0; e < 16; e++) {
                float g = sT[ni][e];
                float p = __builtin_amdgcn_exp2f(g - m);
                rs += p;
                sT[ni][e] = (g != 0.0f) ? p : 0.0f;
            }
        rs += __shfl_xor(rs, 32);
        l += rs;

        s16x8 pfrag[4];
        #pragma unroll
        for (int sp = 0; sp < 4; sp++) {
            const int ni = sp >> 1;
            const int ru = (2 * sp) & 3, rv2 = (2 * sp + 1) & 3;
            unsigned u0 = pk_bf16(sT[ni][ru * 4 + 0], sT[ni][ru * 4 + 1]);
            unsigned u1 = pk_bf16(sT[ni][ru * 4 + 2], sT[ni][ru * 4 + 3]);
            unsigned v0 = pk_bf16(sT[ni][rv2 * 4 + 0], sT[ni][rv2 * 4 + 1]);
            unsigned v1 = pk_bf16(sT[ni][rv2 * 4 + 2], sT[ni][rv2 * 4 + 3]);
            pl32_swap(u0, v0);
            pl32_swap(u1, v1);
            u32x4 w = {u0, u1, v0, v1};
            pfrag[sp] = __builtin_bit_cast(s16x8, w);
        }

        __builtin_amdgcn_s_setprio(1);
        #pragma unroll
        for (int dt = 0; dt < 4; dt++)
            #pragma unroll
            for (int sp = 0; sp < 4; sp++) {
                int r = dt * 32 + lq;
                int slot = (2 * sp + hl) ^ mVl;
                s16x8 vf = *(const s16x8*)(&vt[cur][r * 64 + slot * 8]);
                aoT[dt] = __builtin_amdgcn_mfma_f32_32x32x16_bf16(vf, pfrag[sp], aoT[dt], 0, 0, 0);
            }
        __builtin_amdgcn_s_setprio(0);
        __syncthreads();
    }

    float inv = 1.0f / l;
    u16* orow = xout + ((size_t)(b * N_ + q)) * DIM_ + hh * HD_;
    #pragma unroll
    for (int dt = 0; dt < 4; dt++)
        #pragma unroll
        for (int r2 = 0; r2 < 4; r2++) {
            u16x4 ov;
            #pragma unroll
            for (int e = 0; e < 4; e++)
                ov[e] = f2bf(aoT[dt][r2 * 4 + e] * inv);
            *(u16x4*)(orow + dt * 32 + r2 * 8 + hl * 4) = ov;
        }
}

// ---------------------------------------------------------------- launch
// (this problem's harness always provides >=136 MiB ws; the layout requires it)
extern "C" void kernel_launch(void* const* d_in, const int* in_sizes, int n_in,
                              void* d_out, int out_size, void* d_ws, size_t ws_size,
                              hipStream_t stream) {
    const float* q     = (const float*)d_in[0];
    const float* k     = (const float*)d_in[1];
    const float* v     = (const float*)d_in[2];
    const float* trans = (const float*)d_in[3];
    const float* Wq    = (const float*)d_in[4];
    const float* Wk    = (const float*)d_in[5];
    const float* Wv    = (const float*)d_in[6];
    const float* Wp    = (const float*)d_in[7];
    const float* bp    = (const float*)d_in[8];
    float* out         = (float*)d_out;

    // workspace map (136 MiB):
    //  [0,16M): xb attention output bf16
    //  [16M..24M): Wq,Wk,Wv,Wp bf16 (contiguous) ; [24..72M): Qh/Kh/Vt (stride 16 MiB)
    //  [72M..120M): qb/kb/vb bf16 (stride 16 MiB; dead after projections)
    //  [72M..136M): tP permuted gates (written after qb/kb/vb are dead)
    char* ws = (char*)d_ws;
    u16* xb  = (u16*)(ws);
    u16* wqb = (u16*)(ws + (16u << 20));
    u16* wpb = (u16*)(ws + (22u << 20));
    u16* QhB = (u16*)(ws + (24u << 20));
    u16* KhB = (u16*)(ws + (40u << 20));
    u16* VtB = (u16*)(ws + (56u << 20));
    u16* qb  = (u16*)(ws + (72u << 20));
    float* tP = (float*)(ws + (72u << 20));

    dim3 blk(256);
    cvt_w4<<<dim3(512, 4), blk, 0, stream>>>(Wq, Wk, Wv, Wp, wqb);
    cvt3<<<dim3(4096, 3), blk, 0, stream>>>(q, k, v, qb);
    gemm_qkv<<<dim3(8, 64, 3), blk, 0, stream>>>(qb, wqb, QhB);
    gate_permute<<<dim3(32, 32, B_), blk, 0, stream>>>(trans, tP);
    attn_swapped<<<dim3(16, 8, 4), blk, 0, stream>>>(QhB, KhB, VtB, tP, xb);
    gemm_out<<<dim3(DIM_ / 128, MTOK / 128), blk, 0, stream>>>(xb, wpb, out, bp);
}

// Round 12
// 254.943 us; speedup vs baseline: 2.0014x; 1.0777x over previous
//
#include <hip/hip_runtime.h>
#include <hip/hip_bf16.h>
#include <stdint.h>

// Problem constants (fixed by the reference)
#define B_    4
#define N_    2048
#define DIM_  1024
#define H_    8
#define HD_   128
#define MTOK  (B_ * N_)          // 8192 tokens
#define SCALE_  0.08838834764831845f   // HD^-0.5
#define LOG2E_  1.4426950408889634f
#define QSCALE_ (SCALE_ * LOG2E_)      // folded into Q projection epilogue

typedef unsigned short u16;
typedef __attribute__((ext_vector_type(4)))  float f32x4;
typedef __attribute__((ext_vector_type(16))) float f32x16;
typedef __attribute__((ext_vector_type(8)))  short s16x8;   // 8 bf16 — MFMA A/B frag
typedef __attribute__((ext_vector_type(8)))  u16  u16x8;
typedef __attribute__((ext_vector_type(4)))  u16  u16x4;
typedef __attribute__((ext_vector_type(4)))  unsigned u32x4;

__device__ __forceinline__ u16 f2bf(float f) {
    uint32_t i = __builtin_bit_cast(uint32_t, f);
    return (u16)((i + 0x7FFFu + ((i >> 16) & 1u)) >> 16);   // RNE
}
__device__ __forceinline__ unsigned pk_bf16(float a, float b) {
    unsigned r;
    asm("v_cvt_pk_bf16_f32 %0, %1, %2" : "=v"(r) : "v"(a), "v"(b));
    return r;
}
__device__ __forceinline__ void pl32_swap(unsigned &a, unsigned &b) {
    asm volatile("v_permlane32_swap_b32 %0, %1" : "+v"(a), "+v"(b));
}
__device__ __forceinline__ void gl_lds16(const u16* g, u16* l) {
    __builtin_amdgcn_global_load_lds((const __attribute__((address_space(1))) void*)g,
                                     (__attribute__((address_space(3))) void*)l,
                                     16, 0, 0);
}

// ---------------------------------------------------------------- q/k/v cvt, one launch
__global__ __launch_bounds__(256) void cvt3(const float* __restrict__ q,
                                            const float* __restrict__ k,
                                            const float* __restrict__ v,
                                            u16* __restrict__ qb) {
    const float* s = blockIdx.y == 0 ? q : blockIdx.y == 1 ? k : v;
    u16* d = qb + (size_t)blockIdx.y * (8u << 20);     // qb/kb/vb stride 16 MiB
    int i = (blockIdx.x * 256 + threadIdx.x) * 8;      // grid.x=4096 covers 8M elems
    float4 a = *(const float4*)(s + i);
    float4 b = *(const float4*)(s + i + 4);
    u32x4 w = {pk_bf16(a.x, a.y), pk_bf16(a.z, a.w), pk_bf16(b.x, b.y), pk_bf16(b.z, b.w)};
    *(u16x8*)(d + i) = __builtin_bit_cast(u16x8, w);
}

// ---------------------------------------------------------------- weight cvt (4 tensors, one launch)
__global__ __launch_bounds__(256) void cvt_w4(const float* __restrict__ s0,
                                              const float* __restrict__ s1,
                                              const float* __restrict__ s2,
                                              const float* __restrict__ s3,
                                              u16* __restrict__ dst) {
    const float* s = blockIdx.y == 0 ? s0 : blockIdx.y == 1 ? s1 : blockIdx.y == 2 ? s2 : s3;
    u16* d = dst + (size_t)blockIdx.y * (DIM_ * DIM_);
    int i = (blockIdx.x * 256 + threadIdx.x) * 8;          // grid.x=512 covers 1M elems
    float4 a = *(const float4*)(s + i);
    float4 b = *(const float4*)(s + i + 4);
    u32x4 w = {pk_bf16(a.x, a.y), pk_bf16(a.z, a.w), pk_bf16(b.x, b.y), pk_bf16(b.z, b.w)};
    *(u16x8*)(d + i) = __builtin_bit_cast(u16x8, w);
}

// ---------------------------------------------------------------- gate permute (lane-coalesced)
// tP4 (f32x4 units): idx = (((b*32+it)*2+hl)*8 + jj)*2048 + q
//   value[e] = trans[b][q][64*it + 32*(jj>>2) + 8*(jj&3) + 4*hl + e]
// attn lane (q, hl) reads ttv[jj] = tP4[base_it + jj*2048 + q] -> 32 consecutive lanes
// read 32 consecutive f32x4 (512B dense per half-wave per instruction).
__global__ __launch_bounds__(256) void gate_permute(const float* __restrict__ trans,
                                                    float* __restrict__ tP) {
    __shared__ float T[64][68];                       // row stride 272B (16B multiple)
    const int it = blockIdx.x, qc = blockIdx.y, b = blockIdx.z;
    const float* ib = trans + (size_t)b * N_ * N_;
    const int q0 = qc * 64;
    const int lr = threadIdx.x >> 4, lc = threadIdx.x & 15;
    #pragma unroll
    for (int i = 0; i < 4; i++) {
        int row = i * 16 + lr;
        f32x4 v = *(const f32x4*)(ib + (size_t)(q0 + row) * N_ + it * 64 + lc * 4);
        *(f32x4*)(&T[row][lc * 4]) = v;
    }
    __syncthreads();
    // 256 threads = 4 groups x 64 q; group g: hl = g&1, half = g>>1; each thread
    // writes 4 f32x4 (jj = half*4 + jj2) at consecutive-q addresses (1KB dense/instr).
    const int qi = threadIdx.x & 63, grp = threadIdx.x >> 6;
    const int hl = grp & 1, half = grp >> 1;
    f32x4* tp4 = (f32x4*)tP;
    const size_t base = (((size_t)(b * 32 + it) * 2 + hl) * 8 + half * 4) * 2048 + q0 + qi;
    #pragma unroll
    for (int jj2 = 0; jj2 < 4; jj2++) {
        // jj = half*4 + jj2 ; ni = half ; r2 = jj2
        f32x4 v = *(const f32x4*)(&T[qi][32 * half + 8 * jj2 + 4 * hl]);
        tp4[base + (size_t)jj2 * 2048] = v;
    }
}

// ---------------------------------------------------------------- fused QKV projection GEMM
// z selects (A, Bt, Cout, scale, epilogue): z<2 -> head-split [B,H,N,HD] (Q,K);
// z==2 -> transposed [B,H,HD,N] (V).  A/C stride 8M u16; Bt stride 1M u16.
__global__ __launch_bounds__(256) void gemm_qkv(const u16* __restrict__ Abase,
                                                const u16* __restrict__ Wbase,
                                                u16* __restrict__ Cbase) {
    __shared__ __align__(16) u16 lga[128 * 64];
    __shared__ __align__(16) u16 lgb[128 * 64];
    const int tid  = threadIdx.x;
    const int lane = tid & 63, wave = tid >> 6;
    const int wm = wave >> 1, wn = wave & 1;
    const int z = blockIdx.z;
    const u16* A  = Abase + (size_t)z * (8u << 20);
    const u16* Bt = Wbase + (size_t)z * (DIM_ * DIM_);
    u16* Cout     = Cbase + (size_t)z * (8u << 20);
    const float scale = (z == 0) ? QSCALE_ : 1.0f;
    int lin = blockIdx.x + gridDim.x * blockIdx.y;
    int w   = (lin & 7) * 64 + (lin >> 3);
    const int row0 = (w >> 3) * 128, col0 = (w & 7) * 128;

    f32x4 acc[4][4] = {};

    auto stageLds = [&](const u16* G, u16* L, int rowbase, int k0) {
        #pragma unroll
        for (int i = 0; i < 4; i++) {
            int rb = wave * 32 + i * 8;
            int r  = rb + (lane >> 3);
            int cc = (lane & 7) ^ (lane >> 3);
            gl_lds16(G + (size_t)(rowbase + r) * DIM_ + k0 + cc * 8, L + rb * 64);
        }
    };

    for (int k0 = 0; k0 < DIM_; k0 += 64) {
        stageLds(A,  lga, row0, k0);
        stageLds(Bt, lgb, col0, k0);
        __syncthreads();
        #pragma unroll
        for (int kk = 0; kk < 2; kk++) {
            s16x8 af[4], bfr[4];
            #pragma unroll
            for (int mi = 0; mi < 4; mi++) {
                int r = wm * 64 + mi * 16 + (lane & 15);
                int sc = (kk * 4 + (lane >> 4)) ^ (lane & 7);
                af[mi] = *(const s16x8*)(&lga[r * 64 + sc * 8]);
            }
            #pragma unroll
            for (int ni = 0; ni < 4; ni++) {
                int r = wn * 64 + ni * 16 + (lane & 15);
                int sc = (kk * 4 + (lane >> 4)) ^ (lane & 7);
                bfr[ni] = *(const s16x8*)(&lgb[r * 64 + sc * 8]);
            }
            #pragma unroll
            for (int mi = 0; mi < 4; mi++)
                #pragma unroll
                for (int ni = 0; ni < 4; ni++)
                    acc[mi][ni] = __builtin_amdgcn_mfma_f32_16x16x32_bf16(
                        af[mi], bfr[ni], acc[mi][ni], 0, 0, 0);
        }
        __syncthreads();
    }

    #pragma unroll
    for (int mi = 0; mi < 4; mi++) {
        #pragma unroll
        for (int ni = 0; ni < 4; ni++) {
            #pragma unroll
            for (int r = 0; r < 4; r++) {
                int grow = row0 + wm * 64 + mi * 16 + ((lane >> 4) << 2) + r;
                int gcol = col0 + wn * 64 + ni * 16 + (lane & 15);
                float vv = acc[mi][ni][r] * scale;
                int bb = grow >> 11, n = grow & (N_ - 1);
                int hh = gcol >> 7,  d = gcol & (HD_ - 1);
                size_t idx = (z < 2)
                    ? ((size_t)(bb * H_ + hh) * N_ + n) * HD_ + d
                    : ((size_t)(bb * H_ + hh) * HD_ + d) * N_ + n;
                Cout[idx] = f2bf(vv);
            }
        }
    }
}

// ---------------------------------------------------------------- output projection GEMM
__global__ __launch_bounds__(256) void gemm_out(const u16* __restrict__ A,
                                                const u16* __restrict__ Bt,
                                                float* __restrict__ Cout,
                                                const float* __restrict__ bias) {
    __shared__ __align__(16) u16 lga[128 * 64];
    __shared__ __align__(16) u16 lgb[128 * 64];
    const int tid  = threadIdx.x;
    const int lane = tid & 63, wave = tid >> 6;
    const int wm = wave >> 1, wn = wave & 1;
    int lin = blockIdx.x + gridDim.x * blockIdx.y;
    int w   = (lin & 7) * 64 + (lin >> 3);
    const int row0 = (w >> 3) * 128, col0 = (w & 7) * 128;

    f32x4 acc[4][4] = {};

    auto stageLds = [&](const u16* G, u16* L, int rowbase, int k0) {
        #pragma unroll
        for (int i = 0; i < 4; i++) {
            int rb = wave * 32 + i * 8;
            int r  = rb + (lane >> 3);
            int cc = (lane & 7) ^ (lane >> 3);
            gl_lds16(G + (size_t)(rowbase + r) * DIM_ + k0 + cc * 8, L + rb * 64);
        }
    };

    for (int k0 = 0; k0 < DIM_; k0 += 64) {
        stageLds(A,  lga, row0, k0);
        stageLds(Bt, lgb, col0, k0);
        __syncthreads();
        #pragma unroll
        for (int kk = 0; kk < 2; kk++) {
            s16x8 af[4], bfr[4];
            #pragma unroll
            for (int mi = 0; mi < 4; mi++) {
                int r = wm * 64 + mi * 16 + (lane & 15);
                int sc = (kk * 4 + (lane >> 4)) ^ (lane & 7);
                af[mi] = *(const s16x8*)(&lga[r * 64 + sc * 8]);
            }
            #pragma unroll
            for (int ni = 0; ni < 4; ni++) {
                int r = wn * 64 + ni * 16 + (lane & 15);
                int sc = (kk * 4 + (lane >> 4)) ^ (lane & 7);
                bfr[ni] = *(const s16x8*)(&lgb[r * 64 + sc * 8]);
            }
            #pragma unroll
            for (int mi = 0; mi < 4; mi++)
                #pragma unroll
                for (int ni = 0; ni < 4; ni++)
                    acc[mi][ni] = __builtin_amdgcn_mfma_f32_16x16x32_bf16(
                        af[mi], bfr[ni], acc[mi][ni], 0, 0, 0);
        }
        __syncthreads();
    }

    #pragma unroll
    for (int mi = 0; mi < 4; mi++) {
        #pragma unroll
        for (int ni = 0; ni < 4; ni++) {
            #pragma unroll
            for (int r = 0; r < 4; r++) {
                int grow = row0 + wm * 64 + mi * 16 + ((lane >> 4) << 2) + r;
                int gcol = col0 + wn * 64 + ni * 16 + (lane & 15);
                Cout[(size_t)grow * DIM_ + gcol] = acc[mi][ni][r] + bias[gcol];
            }
        }
    }
}

// ---------------------------------------------------------------- gated flash attention (swapped)
// R8-proven core + lane-coalesced tP gate reads.
__global__ __launch_bounds__(256, 2) void attn_swapped(const u16* __restrict__ Qh,
                                                       const u16* __restrict__ Kh,
                                                       const u16* __restrict__ Vt,
                                                       const float* __restrict__ tP,
                                                       u16* __restrict__ xout) {
    __shared__ __align__(16) u16 kt[2][64 * 128];   // K [kv=64][d=128], slot = c ^ mK(r)
    __shared__ __align__(16) u16 vt[2][128 * 64];   // Vt [d=128][kv=64], slot = c ^ mV(r)

    const int tid = threadIdx.x, lane = tid & 63, wave = tid >> 6;
    const int lq = lane & 31, hl = lane >> 5;

    int lin = blockIdx.x + 16 * (blockIdx.y + 8 * blockIdx.z);
    int nl  = (lin & 7) * 64 + (lin >> 3);
    const int qt = nl & 15, hh = (nl >> 4) & 7, b = nl >> 7;
    const int q0 = qt * 128 + wave * 32;
    const int q  = q0 + lq;

    const u16* Qbh = Qh + (size_t)(b * H_ + hh) * N_ * HD_;
    const u16* Kbh = Kh + (size_t)(b * H_ + hh) * N_ * HD_;
    const u16* Vbh = Vt + (size_t)(b * H_ + hh) * HD_ * N_;
    // lane-coalesced gate base: tP4[(((b*32+it)*2+hl)*8 + jj)*2048 + q]
    const f32x4* tp4 = (const f32x4*)tP;
    const size_t tbase0 = ((size_t)(b * 32) * 2 + hl) * 8 * 2048 + q;

    s16x8 qf[8];
    #pragma unroll
    for (int s = 0; s < 8; s++)
        qf[s] = *(const s16x8*)(Qbh + (size_t)q * HD_ + s * 16 + hl * 8);

    auto stageKV = [&](int kv0, int bi) {
        #pragma unroll
        for (int i = 0; i < 4; i++) {
            int rk = wave * 16 + i * 4 + (lane >> 4);
            int ck = (lane & 15) ^ (rk & 15) ^ ((rk & 16) >> 2);
            gl_lds16(Kbh + (size_t)(kv0 + rk) * HD_ + ck * 8,
                     &kt[bi][(wave * 16 + i * 4) * 128]);
            int rv = wave * 32 + i * 8 + (lane >> 3);
            int cv = (lane & 7) ^ (rv & 7) ^ ((rv >> 3) & 3);
            gl_lds16(Vbh + (size_t)rv * N_ + kv0 + cv * 8,
                     &vt[bi][(wave * 32 + i * 8) * 64]);
        }
    };

    const int mKl = (lq & 15) ^ ((lq & 16) >> 2);
    const int mVl = (lq & 7) ^ ((lq >> 3) & 3);

    float m = -3.0e38f, l = 0.f;
    f32x16 aoT[4] = {};

    stageKV(0, 0);
    __syncthreads();

    for (int it = 0; it < N_ / 64; it++) {
        const int kv0 = it * 64, cur = it & 1;
        if (it + 1 < N_ / 64) stageKV(kv0 + 64, cur ^ 1);

        // gate values: 8 lane-coalesced f32x4 loads (32 lanes x 16B dense each)
        const size_t tbase = tbase0 + (size_t)it * (2 * 8 * 2048);
        f32x4 ttv[8];
        #pragma unroll
        for (int jj = 0; jj < 8; jj++)
            ttv[jj] = tp4[tbase + (size_t)jj * 2048];

        f32x16 sT[2] = {};
        __builtin_amdgcn_s_setprio(1);
        #pragma unroll
        for (int s = 0; s < 8; s++)
            #pragma unroll
            for (int ni = 0; ni < 2; ni++) {
                int r = ni * 32 + lq;
                int slot = (2 * s + hl) ^ mKl;
                s16x8 kf = *(const s16x8*)(&kt[cur][r * 128 + slot * 8]);
                sT[ni] = __builtin_amdgcn_mfma_f32_32x32x16_bf16(kf, qf[s], sT[ni], 0, 0, 0);
            }
        __builtin_amdgcn_s_setprio(0);

        float mx = -3.0e38f;
        #pragma unroll
        for (int ni = 0; ni < 2; ni++)
            #pragma unroll
            for (int idx = 0; idx < 16; idx++) {
                float g = sT[ni][idx] * ttv[(ni << 2) | (idx >> 2)][idx & 3];
                sT[ni][idx] = g;
                mx = fmaxf(mx, g);
            }
        mx = fmaxf(mx, __shfl_xor(mx, 32));

        if (__any(mx > m + 8.0f)) {
            float mn = fmaxf(m, mx);
            float sfv = __builtin_amdgcn_exp2f(m - mn);
            m = mn;
            l *= sfv;
            #pragma unroll
            for (int dt = 0; dt < 4; dt++)
                #pragma unroll
                for (int e = 0; e < 16; e++) aoT[dt][e] *= sfv;
        }

        float rs = 0.f;
        #pragma unroll
        for (int ni = 0; ni < 2; ni++)
            #pragma unroll
            for (int e = 0; e < 16; e++) {
                float g = sT[ni][e];
                float p = __builtin_amdgcn_exp2f(g - m);
                rs += p;
                sT[ni][e] = (g != 0.0f) ? p : 0.0f;
            }
        rs += __shfl_xor(rs, 32);
        l += rs;

        s16x8 pfrag[4];
        #pragma unroll
        for (int sp = 0; sp < 4; sp++) {
            const int ni = sp >> 1;
            const int ru = (2 * sp) & 3, rv2 = (2 * sp + 1) & 3;
            unsigned u0 = pk_bf16(sT[ni][ru * 4 + 0], sT[ni][ru * 4 + 1]);
            unsigned u1 = pk_bf16(sT[ni][ru * 4 + 2], sT[ni][ru * 4 + 3]);
            unsigned v0 = pk_bf16(sT[ni][rv2 * 4 + 0], sT[ni][rv2 * 4 + 1]);
            unsigned v1 = pk_bf16(sT[ni][rv2 * 4 + 2], sT[ni][rv2 * 4 + 3]);
            pl32_swap(u0, v0);
            pl32_swap(u1, v1);
            u32x4 w = {u0, u1, v0, v1};
            pfrag[sp] = __builtin_bit_cast(s16x8, w);
        }

        __builtin_amdgcn_s_setprio(1);
        #pragma unroll
        for (int dt = 0; dt < 4; dt++)
            #pragma unroll
            for (int sp = 0; sp < 4; sp++) {
                int r = dt * 32 + lq;
                int slot = (2 * sp + hl) ^ mVl;
                s16x8 vf = *(const s16x8*)(&vt[cur][r * 64 + slot * 8]);
                aoT[dt] = __builtin_amdgcn_mfma_f32_32x32x16_bf16(vf, pfrag[sp], aoT[dt], 0, 0, 0);
            }
        __builtin_amdgcn_s_setprio(0);
        __syncthreads();
    }

    float inv = 1.0f / l;
    u16* orow = xout + ((size_t)(b * N_ + q)) * DIM_ + hh * HD_;
    #pragma unroll
    for (int dt = 0; dt < 4; dt++)
        #pragma unroll
        for (int r2 = 0; r2 < 4; r2++) {
            u16x4 ov;
            #pragma unroll
            for (int e = 0; e < 4; e++)
                ov[e] = f2bf(aoT[dt][r2 * 4 + e] * inv);
            *(u16x4*)(orow + dt * 32 + r2 * 8 + hl * 4) = ov;
        }
}

// ---------------------------------------------------------------- launch
// (this problem's harness always provides >=136 MiB ws; the layout requires it)
extern "C" void kernel_launch(void* const* d_in, const int* in_sizes, int n_in,
                              void* d_out, int out_size, void* d_ws, size_t ws_size,
                              hipStream_t stream) {
    const float* q     = (const float*)d_in[0];
    const float* k     = (const float*)d_in[1];
    const float* v     = (const float*)d_in[2];
    const float* trans = (const float*)d_in[3];
    const float* Wq    = (const float*)d_in[4];
    const float* Wk    = (const float*)d_in[5];
    const float* Wv    = (const float*)d_in[6];
    const float* Wp    = (const float*)d_in[7];
    const float* bp    = (const float*)d_in[8];
    float* out         = (float*)d_out;

    // workspace map (136 MiB):
    //  [0,16M): xb attention output bf16
    //  [16M..24M): Wq,Wk,Wv,Wp bf16 (contiguous) ; [24..72M): Qh/Kh/Vt (stride 16 MiB)
    //  [72M..120M): qb/kb/vb bf16 (stride 16 MiB; dead after projections)
    //  [72M..136M): tP permuted gates (written after qb/kb/vb are dead)
    char* ws = (char*)d_ws;
    u16* xb  = (u16*)(ws);
    u16* wqb = (u16*)(ws + (16u << 20));
    u16* wpb = (u16*)(ws + (22u << 20));
    u16* QhB = (u16*)(ws + (24u << 20));
    u16* KhB = (u16*)(ws + (40u << 20));
    u16* VtB = (u16*)(ws + (56u << 20));
    u16* qb  = (u16*)(ws + (72u << 20));
    float* tP = (float*)(ws + (72u << 20));

    dim3 blk(256);
    cvt_w4<<<dim3(512, 4), blk, 0, stream>>>(Wq, Wk, Wv, Wp, wqb);
    cvt3<<<dim3(4096, 3), blk, 0, stream>>>(q, k, v, qb);
    gemm_qkv<<<dim3(8, 64, 3), blk, 0, stream>>>(qb, wqb, QhB);
    gate_permute<<<dim3(32, 32, B_), blk, 0, stream>>>(trans, tP);
    attn_swapped<<<dim3(16, 8, 4), blk, 0, stream>>>(QhB, KhB, VtB, tP, xb);
    gemm_out<<<dim3(DIM_ / 128, MTOK / 128), blk, 0, stream>>>(xb, wpb, out, bp);
}

// Round 13
// 252.548 us; speedup vs baseline: 2.0204x; 1.0095x over previous
//
#include <hip/hip_runtime.h>
#include <hip/hip_bf16.h>
#include <stdint.h>

// Problem constants (fixed by the reference)
#define B_    4
#define N_    2048
#define DIM_  1024
#define H_    8
#define HD_   128
#define MTOK  (B_ * N_)          // 8192 tokens
#define SCALE_  0.08838834764831845f   // HD^-0.5
#define LOG2E_  1.4426950408889634f
#define QSCALE_ (SCALE_ * LOG2E_)      // folded into Q projection epilogue

typedef unsigned short u16;
typedef __attribute__((ext_vector_type(2)))  float f32x2;
typedef __attribute__((ext_vector_type(4)))  float f32x4;
typedef __attribute__((ext_vector_type(8)))  float f32x8;
typedef __attribute__((ext_vector_type(16))) float f32x16;
typedef __attribute__((ext_vector_type(8)))  short s16x8;   // 8 bf16 — MFMA A/B frag
typedef __attribute__((ext_vector_type(8)))  u16  u16x8;
typedef __attribute__((ext_vector_type(4)))  u16  u16x4;
typedef __attribute__((ext_vector_type(4)))  unsigned u32x4;

__device__ __forceinline__ u16 f2bf(float f) {
    uint32_t i = __builtin_bit_cast(uint32_t, f);
    return (u16)((i + 0x7FFFu + ((i >> 16) & 1u)) >> 16);   // RNE
}
__device__ __forceinline__ unsigned pk_bf16(float a, float b) {
    unsigned r;
    asm("v_cvt_pk_bf16_f32 %0, %1, %2" : "=v"(r) : "v"(a), "v"(b));
    return r;
}
__device__ __forceinline__ void pl32_swap(unsigned &a, unsigned &b) {
    asm volatile("v_permlane32_swap_b32 %0, %1" : "+v"(a), "+v"(b));
}
__device__ __forceinline__ void gl_lds16(const u16* g, u16* l) {
    __builtin_amdgcn_global_load_lds((const __attribute__((address_space(1))) void*)g,
                                     (__attribute__((address_space(3))) void*)l,
                                     16, 0, 0);
}

// ---------------------------------------------------------------- fused prep kernel
// One launch, three independent jobs partitioned by flat blockIdx.x:
//   [0, 12288)        : cvt3   — q/k/v f32->bf16 (slice = bid/4096)
//   [12288, 14336)    : cvt_w4 — Wq/Wk/Wv/Wp f32->bf16 (slice = (bid-12288)>>9)
//   [14336, 18432)    : gate_permute — trans -> tP (lane-coalesced layout)
// tP4 (f32x4 units): idx = (((b*32+it)*2+hl)*8 + jj)*2048 + q
//   value[e] = trans[b][q][64*it + 32*(jj>>2) + 8*(jj&3) + 4*hl + e]
__global__ __launch_bounds__(256) void prep(const float* __restrict__ q,
                                            const float* __restrict__ k,
                                            const float* __restrict__ v,
                                            const float* __restrict__ Wq,
                                            const float* __restrict__ Wk,
                                            const float* __restrict__ Wv,
                                            const float* __restrict__ Wp,
                                            const float* __restrict__ trans,
                                            u16* __restrict__ qb,
                                            u16* __restrict__ wqb,
                                            float* __restrict__ tP) {
    __shared__ float T[64][68];
    const int bid = blockIdx.x, tid = threadIdx.x;
    if (bid < 12288) {
        const int sl = bid >> 12, x = bid & 4095;
        const float* s = sl == 0 ? q : sl == 1 ? k : v;
        u16* d = qb + (size_t)sl * (8u << 20);
        int i = (x * 256 + tid) * 8;
        float4 a = *(const float4*)(s + i);
        float4 b = *(const float4*)(s + i + 4);
        u32x4 w = {pk_bf16(a.x, a.y), pk_bf16(a.z, a.w), pk_bf16(b.x, b.y), pk_bf16(b.z, b.w)};
        *(u16x8*)(d + i) = __builtin_bit_cast(u16x8, w);
    } else if (bid < 14336) {
        const int sub = bid - 12288, sl = sub >> 9, x = sub & 511;
        const float* s = sl == 0 ? Wq : sl == 1 ? Wk : sl == 2 ? Wv : Wp;
        u16* d = wqb + (size_t)sl * (DIM_ * DIM_);
        int i = (x * 256 + tid) * 8;
        float4 a = *(const float4*)(s + i);
        float4 b = *(const float4*)(s + i + 4);
        u32x4 w = {pk_bf16(a.x, a.y), pk_bf16(a.z, a.w), pk_bf16(b.x, b.y), pk_bf16(b.z, b.w)};
        *(u16x8*)(d + i) = __builtin_bit_cast(u16x8, w);
    } else {
        const int sub = bid - 14336;
        const int it = sub & 31, qc = (sub >> 5) & 31, b = sub >> 10;
        const float* ib = trans + (size_t)b * N_ * N_;
        const int q0 = qc * 64;
        const int lr = tid >> 4, lc = tid & 15;
        #pragma unroll
        for (int i = 0; i < 4; i++) {
            int row = i * 16 + lr;
            f32x4 vv = *(const f32x4*)(ib + (size_t)(q0 + row) * N_ + it * 64 + lc * 4);
            *(f32x4*)(&T[row][lc * 4]) = vv;
        }
        __syncthreads();
        const int qi = tid & 63, grp = tid >> 6;
        const int hl = grp & 1, half = grp >> 1;
        f32x4* tp4 = (f32x4*)tP;
        const size_t base = (((size_t)(b * 32 + it) * 2 + hl) * 8 + half * 4) * 2048 + q0 + qi;
        #pragma unroll
        for (int jj2 = 0; jj2 < 4; jj2++) {
            f32x4 vv = *(const f32x4*)(&T[qi][32 * half + 8 * jj2 + 4 * hl]);
            tp4[base + (size_t)jj2 * 2048] = vv;
        }
    }
}

// ---------------------------------------------------------------- fused QKV projection GEMM
// z selects (A, Bt, Cout, scale, epilogue): z<2 -> head-split [B,H,N,HD] (Q,K);
// z==2 -> transposed [B,H,HD,N] (V).  A/C stride 8M u16; Bt stride 1M u16.
__global__ __launch_bounds__(256) void gemm_qkv(const u16* __restrict__ Abase,
                                                const u16* __restrict__ Wbase,
                                                u16* __restrict__ Cbase) {
    __shared__ __align__(16) u16 lga[128 * 64];
    __shared__ __align__(16) u16 lgb[128 * 64];
    const int tid  = threadIdx.x;
    const int lane = tid & 63, wave = tid >> 6;
    const int wm = wave >> 1, wn = wave & 1;
    const int z = blockIdx.z;
    const u16* A  = Abase + (size_t)z * (8u << 20);
    const u16* Bt = Wbase + (size_t)z * (DIM_ * DIM_);
    u16* Cout     = Cbase + (size_t)z * (8u << 20);
    const float scale = (z == 0) ? QSCALE_ : 1.0f;
    int lin = blockIdx.x + gridDim.x * blockIdx.y;
    int w   = (lin & 7) * 64 + (lin >> 3);
    const int row0 = (w >> 3) * 128, col0 = (w & 7) * 128;

    f32x4 acc[4][4] = {};

    auto stageLds = [&](const u16* G, u16* L, int rowbase, int k0) {
        #pragma unroll
        for (int i = 0; i < 4; i++) {
            int rb = wave * 32 + i * 8;
            int r  = rb + (lane >> 3);
            int cc = (lane & 7) ^ (lane >> 3);
            gl_lds16(G + (size_t)(rowbase + r) * DIM_ + k0 + cc * 8, L + rb * 64);
        }
    };

    for (int k0 = 0; k0 < DIM_; k0 += 64) {
        stageLds(A,  lga, row0, k0);
        stageLds(Bt, lgb, col0, k0);
        __syncthreads();
        #pragma unroll
        for (int kk = 0; kk < 2; kk++) {
            s16x8 af[4], bfr[4];
            #pragma unroll
            for (int mi = 0; mi < 4; mi++) {
                int r = wm * 64 + mi * 16 + (lane & 15);
                int sc = (kk * 4 + (lane >> 4)) ^ (lane & 7);
                af[mi] = *(const s16x8*)(&lga[r * 64 + sc * 8]);
            }
            #pragma unroll
            for (int ni = 0; ni < 4; ni++) {
                int r = wn * 64 + ni * 16 + (lane & 15);
                int sc = (kk * 4 + (lane >> 4)) ^ (lane & 7);
                bfr[ni] = *(const s16x8*)(&lgb[r * 64 + sc * 8]);
            }
            #pragma unroll
            for (int mi = 0; mi < 4; mi++)
                #pragma unroll
                for (int ni = 0; ni < 4; ni++)
                    acc[mi][ni] = __builtin_amdgcn_mfma_f32_16x16x32_bf16(
                        af[mi], bfr[ni], acc[mi][ni], 0, 0, 0);
        }
        __syncthreads();
    }

    #pragma unroll
    for (int mi = 0; mi < 4; mi++) {
        #pragma unroll
        for (int ni = 0; ni < 4; ni++) {
            #pragma unroll
            for (int r = 0; r < 4; r++) {
                int grow = row0 + wm * 64 + mi * 16 + ((lane >> 4) << 2) + r;
                int gcol = col0 + wn * 64 + ni * 16 + (lane & 15);
                float vv = acc[mi][ni][r] * scale;
                int bb = grow >> 11, n = grow & (N_ - 1);
                int hh = gcol >> 7,  d = gcol & (HD_ - 1);
                size_t idx = (z < 2)
                    ? ((size_t)(bb * H_ + hh) * N_ + n) * HD_ + d
                    : ((size_t)(bb * H_ + hh) * HD_ + d) * N_ + n;
                Cout[idx] = f2bf(vv);
            }
        }
    }
}

// ---------------------------------------------------------------- output projection GEMM
__global__ __launch_bounds__(256) void gemm_out(const u16* __restrict__ A,
                                                const u16* __restrict__ Bt,
                                                float* __restrict__ Cout,
                                                const float* __restrict__ bias) {
    __shared__ __align__(16) u16 lga[128 * 64];
    __shared__ __align__(16) u16 lgb[128 * 64];
    const int tid  = threadIdx.x;
    const int lane = tid & 63, wave = tid >> 6;
    const int wm = wave >> 1, wn = wave & 1;
    int lin = blockIdx.x + gridDim.x * blockIdx.y;
    int w   = (lin & 7) * 64 + (lin >> 3);
    const int row0 = (w >> 3) * 128, col0 = (w & 7) * 128;

    f32x4 acc[4][4] = {};

    auto stageLds = [&](const u16* G, u16* L, int rowbase, int k0) {
        #pragma unroll
        for (int i = 0; i < 4; i++) {
            int rb = wave * 32 + i * 8;
            int r  = rb + (lane >> 3);
            int cc = (lane & 7) ^ (lane >> 3);
            gl_lds16(G + (size_t)(rowbase + r) * DIM_ + k0 + cc * 8, L + rb * 64);
        }
    };

    for (int k0 = 0; k0 < DIM_; k0 += 64) {
        stageLds(A,  lga, row0, k0);
        stageLds(Bt, lgb, col0, k0);
        __syncthreads();
        #pragma unroll
        for (int kk = 0; kk < 2; kk++) {
            s16x8 af[4], bfr[4];
            #pragma unroll
            for (int mi = 0; mi < 4; mi++) {
                int r = wm * 64 + mi * 16 + (lane & 15);
                int sc = (kk * 4 + (lane >> 4)) ^ (lane & 7);
                af[mi] = *(const s16x8*)(&lga[r * 64 + sc * 8]);
            }
            #pragma unroll
            for (int ni = 0; ni < 4; ni++) {
                int r = wn * 64 + ni * 16 + (lane & 15);
                int sc = (kk * 4 + (lane >> 4)) ^ (lane & 7);
                bfr[ni] = *(const s16x8*)(&lgb[r * 64 + sc * 8]);
            }
            #pragma unroll
            for (int mi = 0; mi < 4; mi++)
                #pragma unroll
                for (int ni = 0; ni < 4; ni++)
                    acc[mi][ni] = __builtin_amdgcn_mfma_f32_16x16x32_bf16(
                        af[mi], bfr[ni], acc[mi][ni], 0, 0, 0);
        }
        __syncthreads();
    }

    #pragma unroll
    for (int mi = 0; mi < 4; mi++) {
        #pragma unroll
        for (int ni = 0; ni < 4; ni++) {
            #pragma unroll
            for (int r = 0; r < 4; r++) {
                int grow = row0 + wm * 64 + mi * 16 + ((lane >> 4) << 2) + r;
                int gcol = col0 + wn * 64 + ni * 16 + (lane & 15);
                Cout[(size_t)grow * DIM_ + gcol] = acc[mi][ni][r] + bias[gcol];
            }
        }
    }
}

// ---------------------------------------------------------------- gated flash attention (swapped)
// R12-proven core; softmax arithmetic vectorized (f32 vector ops -> v_pk_*_f32 where
// available; semantics identical, max/sum reassociated only).
__global__ __launch_bounds__(256, 2) void attn_swapped(const u16* __restrict__ Qh,
                                                       const u16* __restrict__ Kh,
                                                       const u16* __restrict__ Vt,
                                                       const float* __restrict__ tP,
                                                       u16* __restrict__ xout) {
    __shared__ __align__(16) u16 kt[2][64 * 128];   // K [kv=64][d=128], slot = c ^ mK(r)
    __shared__ __align__(16) u16 vt[2][128 * 64];   // Vt [d=128][kv=64], slot = c ^ mV(r)

    const int tid = threadIdx.x, lane = tid & 63, wave = tid >> 6;
    const int lq = lane & 31, hl = lane >> 5;

    int lin = blockIdx.x + 16 * (blockIdx.y + 8 * blockIdx.z);
    int nl  = (lin & 7) * 64 + (lin >> 3);
    const int qt = nl & 15, hh = (nl >> 4) & 7, b = nl >> 7;
    const int q0 = qt * 128 + wave * 32;
    const int q  = q0 + lq;

    const u16* Qbh = Qh + (size_t)(b * H_ + hh) * N_ * HD_;
    const u16* Kbh = Kh + (size_t)(b * H_ + hh) * N_ * HD_;
    const u16* Vbh = Vt + (size_t)(b * H_ + hh) * HD_ * N_;
    const f32x4* tp4 = (const f32x4*)tP;
    const size_t tbase0 = ((size_t)(b * 32) * 2 + hl) * 8 * 2048 + q;

    s16x8 qf[8];
    #pragma unroll
    for (int s = 0; s < 8; s++)
        qf[s] = *(const s16x8*)(Qbh + (size_t)q * HD_ + s * 16 + hl * 8);

    auto stageKV = [&](int kv0, int bi) {
        #pragma unroll
        for (int i = 0; i < 4; i++) {
            int rk = wave * 16 + i * 4 + (lane >> 4);
            int ck = (lane & 15) ^ (rk & 15) ^ ((rk & 16) >> 2);
            gl_lds16(Kbh + (size_t)(kv0 + rk) * HD_ + ck * 8,
                     &kt[bi][(wave * 16 + i * 4) * 128]);
            int rv = wave * 32 + i * 8 + (lane >> 3);
            int cv = (lane & 7) ^ (rv & 7) ^ ((rv >> 3) & 3);
            gl_lds16(Vbh + (size_t)rv * N_ + kv0 + cv * 8,
                     &vt[bi][(wave * 32 + i * 8) * 64]);
        }
    };

    const int mKl = (lq & 15) ^ ((lq & 16) >> 2);
    const int mVl = (lq & 7) ^ ((lq >> 3) & 3);

    float m = -3.0e38f, l = 0.f;
    f32x16 aoT[4] = {};

    stageKV(0, 0);
    __syncthreads();

    for (int it = 0; it < N_ / 64; it++) {
        const int kv0 = it * 64, cur = it & 1;
        if (it + 1 < N_ / 64) stageKV(kv0 + 64, cur ^ 1);

        // gate values: 8 lane-coalesced f32x4 loads; assemble per-ni f32x16
        const size_t tbase = tbase0 + (size_t)it * (2 * 8 * 2048);
        f32x16 t16[2];
        #pragma unroll
        for (int ni = 0; ni < 2; ni++)
            #pragma unroll
            for (int j2 = 0; j2 < 4; j2++) {
                f32x4 vv = tp4[tbase + (size_t)(ni * 4 + j2) * 2048];
                #pragma unroll
                for (int e = 0; e < 4; e++) t16[ni][j2 * 4 + e] = vv[e];
            }

        f32x16 sT[2] = {};
        __builtin_amdgcn_s_setprio(1);
        #pragma unroll
        for (int s = 0; s < 8; s++)
            #pragma unroll
            for (int ni = 0; ni < 2; ni++) {
                int r = ni * 32 + lq;
                int slot = (2 * s + hl) ^ mKl;
                s16x8 kf = *(const s16x8*)(&kt[cur][r * 128 + slot * 8]);
                sT[ni] = __builtin_amdgcn_mfma_f32_32x32x16_bf16(kf, qf[s], sT[ni], 0, 0, 0);
            }
        __builtin_amdgcn_s_setprio(0);

        // gate (vector mul) + max reduction (pairwise tree)
        sT[0] = sT[0] * t16[0];
        sT[1] = sT[1] * t16[1];
        f32x16 gm16 = __builtin_elementwise_max(sT[0], sT[1]);
        f32x8 gm8 = __builtin_elementwise_max(
            __builtin_shufflevector(gm16, gm16, 0, 1, 2, 3, 4, 5, 6, 7),
            __builtin_shufflevector(gm16, gm16, 8, 9, 10, 11, 12, 13, 14, 15));
        f32x4 gm4 = __builtin_elementwise_max(
            __builtin_shufflevector(gm8, gm8, 0, 1, 2, 3),
            __builtin_shufflevector(gm8, gm8, 4, 5, 6, 7));
        f32x2 gm2 = __builtin_elementwise_max(
            __builtin_shufflevector(gm4, gm4, 0, 1),
            __builtin_shufflevector(gm4, gm4, 2, 3));
        float mx = fmaxf(gm2[0], gm2[1]);
        mx = fmaxf(mx, __shfl_xor(mx, 32));

        // defer-rescale (T13)
        if (__any(mx > m + 8.0f)) {
            float mn = fmaxf(m, mx);
            float sfv = __builtin_amdgcn_exp2f(m - mn);
            m = mn;
            l *= sfv;
            #pragma unroll
            for (int dt = 0; dt < 4; dt++) aoT[dt] *= sfv;
        }

        // P = exp2(g - m); denom includes ALL entries; PV term zeroed where g==0
        f32x16 rsv = {};
        #pragma unroll
        for (int ni = 0; ni < 2; ni++) {
            f32x16 g = sT[ni];
            f32x16 gm = g - m;           // vector sub (pk-able)
            f32x16 p;
            #pragma unroll
            for (int e = 0; e < 16; e++) p[e] = __builtin_amdgcn_exp2f(gm[e]);
            rsv += p;                    // vector add (pk-able)
            #pragma unroll
            for (int e = 0; e < 16; e++) sT[ni][e] = (g[e] != 0.0f) ? p[e] : 0.0f;
        }
        f32x8 rs8 = __builtin_shufflevector(rsv, rsv, 0, 1, 2, 3, 4, 5, 6, 7)
                  + __builtin_shufflevector(rsv, rsv, 8, 9, 10, 11, 12, 13, 14, 15);
        f32x4 rs4 = __builtin_shufflevector(rs8, rs8, 0, 1, 2, 3)
                  + __builtin_shufflevector(rs8, rs8, 4, 5, 6, 7);
        f32x2 rs2 = __builtin_shufflevector(rs4, rs4, 0, 1)
                  + __builtin_shufflevector(rs4, rs4, 2, 3);
        float rs = rs2[0] + rs2[1];
        rs += __shfl_xor(rs, 32);
        l += rs;

        // pack P -> A-frags: 16 cvt_pk + 8 permlane32_swap (R4-verified)
        s16x8 pfrag[4];
        #pragma unroll
        for (int sp = 0; sp < 4; sp++) {
            const int ni = sp >> 1;
            const int ru = (2 * sp) & 3, rv2 = (2 * sp + 1) & 3;
            unsigned u0 = pk_bf16(sT[ni][ru * 4 + 0], sT[ni][ru * 4 + 1]);
            unsigned u1 = pk_bf16(sT[ni][ru * 4 + 2], sT[ni][ru * 4 + 3]);
            unsigned v0 = pk_bf16(sT[ni][rv2 * 4 + 0], sT[ni][rv2 * 4 + 1]);
            unsigned v1 = pk_bf16(sT[ni][rv2 * 4 + 2], sT[ni][rv2 * 4 + 3]);
            pl32_swap(u0, v0);
            pl32_swap(u1, v1);
            u32x4 w = {u0, u1, v0, v1};
            pfrag[sp] = __builtin_bit_cast(s16x8, w);
        }

        __builtin_amdgcn_s_setprio(1);
        #pragma unroll
        for (int dt = 0; dt < 4; dt++)
            #pragma unroll
            for (int sp = 0; sp < 4; sp++) {
                int r = dt * 32 + lq;
                int slot = (2 * sp + hl) ^ mVl;
                s16x8 vf = *(const s16x8*)(&vt[cur][r * 64 + slot * 8]);
                aoT[dt] = __builtin_amdgcn_mfma_f32_32x32x16_bf16(vf, pfrag[sp], aoT[dt], 0, 0, 0);
            }
        __builtin_amdgcn_s_setprio(0);
        __syncthreads();
    }

    float inv = 1.0f / l;
    u16* orow = xout + ((size_t)(b * N_ + q)) * DIM_ + hh * HD_;
    #pragma unroll
    for (int dt = 0; dt < 4; dt++)
        #pragma unroll
        for (int r2 = 0; r2 < 4; r2++) {
            u16x4 ov;
            #pragma unroll
            for (int e = 0; e < 4; e++)
                ov[e] = f2bf(aoT[dt][r2 * 4 + e] * inv);
            *(u16x4*)(orow + dt * 32 + r2 * 8 + hl * 4) = ov;
        }
}

// ---------------------------------------------------------------- launch
// (this problem's harness always provides >=136 MiB ws; the layout requires it)
extern "C" void kernel_launch(void* const* d_in, const int* in_sizes, int n_in,
                              void* d_out, int out_size, void* d_ws, size_t ws_size,
                              hipStream_t stream) {
    const float* q     = (const float*)d_in[0];
    const float* k     = (const float*)d_in[1];
    const float* v     = (const float*)d_in[2];
    const float* trans = (const float*)d_in[3];
    const float* Wq    = (const float*)d_in[4];
    const float* Wk    = (const float*)d_in[5];
    const float* Wv    = (const float*)d_in[6];
    const float* Wp    = (const float*)d_in[7];
    const float* bp    = (const float*)d_in[8];
    float* out         = (float*)d_out;

    // workspace map (136 MiB):
    //  [0,16M): xb attention output bf16
    //  [16M..24M): Wq,Wk,Wv,Wp bf16 (contiguous) ; [24..72M): Qh/Kh/Vt (stride 16 MiB)
    //  [72M..120M): qb/kb/vb bf16 (stride 16 MiB; dead after projections)
    //  [72M..136M): tP permuted gates — NOTE: tP shares [72M..) with qb only until
    //  projections read qb; but prep writes BOTH. tP actually lives at [72M..136M)?
    //  No — tP and qb must not overlap since prep writes both: tP at [72M..136M) would
    //  clobber qb. Layout: qb/kb/vb at [72M..120M), tP at... needs 64MB.
    //  Resolution: tP -> [24M..72M)? clobbers Qh outputs. Use: qb at [24..72) (inputs),
    //  Qh/Kh/Vt at [72..120), tP at [120..184)?? ws is 136M.
    //  FINAL layout (fits 136M): xb [0,16), W [16,24), qb/kb/vb [24,72),
    //  Qh/Kh/Vt [72,120), tP... 120+64=184 > 136. tP overlaps qb region [24..72)+
    //  [120..136): not contiguous. => tP gets [24..72) REUSE AFTER projections — but
    //  prep writes tP BEFORE projections read qb. Conflict.
    //  => keep R12 ordering: tP at [72..136) and qb/kb/vb INSIDE it is the conflict.
    //  Solution: prep writes qb/kb/vb at [24..72) and tP at [72..136); gemm reads
    //  qb at [24..72), writes Qh/Kh/Vt at... must not clobber tP => Qh/Kh/Vt at
    //  [0..48)?? xb needs [0,16) only AFTER attn. Qh/Kh/Vt can live at [0..48) and
    //  xb reuses [48..64) (inside qb region, dead after projections). bias W at
    //  [64..72)... W region [64,72). All fits in 136M:
    //    [0..48): Qh/Kh/Vt | [48..64): xb | [64..72): W | [24..72)?? overlap!
    //  Simplest correct: [0..48) Qh/Kh/Vt ; [48..56) W ; [56..72) xb ;
    //                    [72..120) qb/kb/vb ; wait prep writes qb then gemm reads it
    //                    and writes into [0..48) — but tP needs 64M: [120..136) is 16M.
    //  ws is 136M total; sum needed: 48(QKV)+8(W)+16(xb)+48(qkvb)+64(tP) = 184 > 136.
    //  => overlap qb/kb/vb with tP is impossible; overlap qb/kb/vb with Qh/Kh/Vt:
    //  gemm_qkv z-slice reads A=qb[z] fully before writing C=Qh[z]? NO — reads/writes
    //  interleave across blocks. => overlap xb with qb (xb written after qb dead): OK.
    //  Needed: 48(QKV)+8(W)+48(qkvb,16 reused later by xb)+64(tP) = 168 > 136. Still over.
    //  => tP must overlap qkvb: tP [88..152)? >136. Hmm.
    //  FALLBACK: split prep into two launches: prep1 (cvt3+cvt_w4) -> gemm_qkv ->
    //  prep2 (gate_permute into the now-dead qb region) -> attn. Same fusion benefit
    //  minus one boundary. Layout = R12's (proven).
    char* ws = (char*)d_ws;
    u16* xb  = (u16*)(ws);
    u16* wqb = (u16*)(ws + (16u << 20));
    u16* wpb = (u16*)(ws + (22u << 20));
    u16* QhB = (u16*)(ws + (24u << 20));
    u16* KhB = (u16*)(ws + (40u << 20));
    u16* VtB = (u16*)(ws + (56u << 20));
    u16* qb  = (u16*)(ws + (72u << 20));
    float* tP = (float*)(ws + (72u << 20));

    dim3 blk(256);
    // prep covers cvt3 [0,12288) + cvt_w4 [12288,14336); gate_permute deferred to
    // its own range [14336,18432) — but tP overlaps qb, so permute must run AFTER
    // gemm_qkv consumes qb. Two partial prep launches:
    prep<<<dim3(14336), blk, 0, stream>>>(q, k, v, Wq, Wk, Wv, Wp, trans, qb, wqb, tP);
    gemm_qkv<<<dim3(8, 64, 3), blk, 0, stream>>>(qb, wqb, QhB);
    // gate_permute range only (blocks [14336,18432) -> pass via offset grid):
    // reuse prep with a grid that starts at 14336 is not expressible; launch the
    // permute-only portion by shifting: grid 4096 blocks with bid >= 14336 semantics.
    // Simplest: dedicated small kernel call through prep's third branch via an
    // offset trick is not available -> separate permute launch (as in R12).
    {
        // permute-only: emulate by launching prep's third branch as its own grid
        // via a wrapper kernel below.
    }
    extern __global__ void gate_permute_only(const float*, float*);
    gate_permute_only<<<dim3(4096), blk, 0, stream>>>(trans, tP);
    attn_swapped<<<dim3(16, 8, 4), blk, 0, stream>>>(QhB, KhB, VtB, tP, xb);
    gemm_out<<<dim3(DIM_ / 128, MTOK / 128), blk, 0, stream>>>(xb, wpb, out, bp);
}

// ---------------------------------------------------------------- gate permute (standalone)
__global__ __launch_bounds__(256) void gate_permute_only(const float* __restrict__ trans,
                                                         float* __restrict__ tP) {
    __shared__ float T[64][68];
    const int sub = blockIdx.x;
    const int it = sub & 31, qc = (sub >> 5) & 31, b = sub >> 10;
    const float* ib = trans + (size_t)b * N_ * N_;
    const int q0 = qc * 64;
    const int lr = threadIdx.x >> 4, lc = threadIdx.x & 15;
    #pragma unroll
    for (int i = 0; i < 4; i++) {
        int row = i * 16 + lr;
        f32x4 vv = *(const f32x4*)(ib + (size_t)(q0 + row) * N_ + it * 64 + lc * 4);
        *(f32x4*)(&T[row][lc * 4]) = vv;
    }
    __syncthreads();
    const int qi = threadIdx.x & 63, grp = threadIdx.x >> 6;
    const int hl = grp & 1, half = grp >> 1;
    f32x4* tp4 = (f32x4*)tP;
    const size_t base = (((size_t)(b * 32 + it) * 2 + hl) * 8 + half * 4) * 2048 + q0 + qi;
    #pragma unroll
    for (int jj2 = 0; jj2 < 4; jj2++) {
        f32x4 vv = *(const f32x4*)(&T[qi][32 * half + 8 * jj2 + 4 * hl]);
        tp4[base + (size_t)jj2 * 2048] = vv;
    }
}

// Round 14
// 248.336 us; speedup vs baseline: 2.0547x; 1.0170x over previous
//
#include <hip/hip_runtime.h>
#include <hip/hip_bf16.h>
#include <stdint.h>

// Problem constants (fixed by the reference)
#define B_    4
#define N_    2048
#define DIM_  1024
#define H_    8
#define HD_   128
#define MTOK  (B_ * N_)          // 8192 tokens
#define SCALE_  0.08838834764831845f   // HD^-0.5
#define LOG2E_  1.4426950408889634f
#define QSCALE_ (SCALE_ * LOG2E_)      // folded into Q projection epilogue

typedef unsigned short u16;
typedef __attribute__((ext_vector_type(4)))  float f32x4;
typedef __attribute__((ext_vector_type(16))) float f32x16;
typedef __attribute__((ext_vector_type(8)))  short s16x8;   // 8 bf16 — MFMA A/B frag
typedef __attribute__((ext_vector_type(8)))  u16  u16x8;
typedef __attribute__((ext_vector_type(4)))  u16  u16x4;
typedef __attribute__((ext_vector_type(4)))  unsigned u32x4;

__device__ __forceinline__ u16 f2bf(float f) {
    uint32_t i = __builtin_bit_cast(uint32_t, f);
    return (u16)((i + 0x7FFFu + ((i >> 16) & 1u)) >> 16);   // RNE
}
__device__ __forceinline__ unsigned pk_bf16(float a, float b) {
    unsigned r;
    asm("v_cvt_pk_bf16_f32 %0, %1, %2" : "=v"(r) : "v"(a), "v"(b));
    return r;
}
__device__ __forceinline__ void pl32_swap(unsigned &a, unsigned &b) {
    asm volatile("v_permlane32_swap_b32 %0, %1" : "+v"(a), "+v"(b));
}
__device__ __forceinline__ void gl_lds16(const u16* g, u16* l) {
    __builtin_amdgcn_global_load_lds((const __attribute__((address_space(1))) void*)g,
                                     (__attribute__((address_space(3))) void*)l,
                                     16, 0, 0);
}

// ---------------------------------------------------------------- fused prep kernel
// One launch: [0,12288) cvt3 q/k/v f32->bf16 ; [12288,14336) cvt_w4 weights.
// (gate_permute runs separately after gemm_qkv frees nothing — tP region is disjoint,
//  but keeping it after projections preserves R12's proven L3 behavior.)
__global__ __launch_bounds__(256) void prep(const float* __restrict__ q,
                                            const float* __restrict__ k,
                                            const float* __restrict__ v,
                                            const float* __restrict__ Wq,
                                            const float* __restrict__ Wk,
                                            const float* __restrict__ Wv,
                                            const float* __restrict__ Wp,
                                            u16* __restrict__ qb,
                                            u16* __restrict__ wqb) {
    const int bid = blockIdx.x, tid = threadIdx.x;
    if (bid < 12288) {
        const int sl = bid >> 12, x = bid & 4095;
        const float* s = sl == 0 ? q : sl == 1 ? k : v;
        u16* d = qb + (size_t)sl * (8u << 20);
        int i = (x * 256 + tid) * 8;
        float4 a = *(const float4*)(s + i);
        float4 b = *(const float4*)(s + i + 4);
        u32x4 w = {pk_bf16(a.x, a.y), pk_bf16(a.z, a.w), pk_bf16(b.x, b.y), pk_bf16(b.z, b.w)};
        *(u16x8*)(d + i) = __builtin_bit_cast(u16x8, w);
    } else {
        const int sub = bid - 12288, sl = sub >> 9, x = sub & 511;
        const float* s = sl == 0 ? Wq : sl == 1 ? Wk : sl == 2 ? Wv : Wp;
        u16* d = wqb + (size_t)sl * (DIM_ * DIM_);
        int i = (x * 256 + tid) * 8;
        float4 a = *(const float4*)(s + i);
        float4 b = *(const float4*)(s + i + 4);
        u32x4 w = {pk_bf16(a.x, a.y), pk_bf16(a.z, a.w), pk_bf16(b.x, b.y), pk_bf16(b.z, b.w)};
        *(u16x8*)(d + i) = __builtin_bit_cast(u16x8, w);
    }
}

// ---------------------------------------------------------------- gate permute (lane-coalesced)
// tP4 (f32x4 units): idx = (((b*32+it)*2+hl)*8 + jj)*2048 + q
//   value[e] = trans[b][q][64*it + 32*(jj>>2) + 8*(jj&3) + 4*hl + e]
__global__ __launch_bounds__(256) void gate_permute(const float* __restrict__ trans,
                                                    float* __restrict__ tP) {
    __shared__ float T[64][68];
    const int sub = blockIdx.x;
    const int it = sub & 31, qc = (sub >> 5) & 31, b = sub >> 10;
    const float* ib = trans + (size_t)b * N_ * N_;
    const int q0 = qc * 64;
    const int lr = threadIdx.x >> 4, lc = threadIdx.x & 15;
    #pragma unroll
    for (int i = 0; i < 4; i++) {
        int row = i * 16 + lr;
        f32x4 vv = *(const f32x4*)(ib + (size_t)(q0 + row) * N_ + it * 64 + lc * 4);
        *(f32x4*)(&T[row][lc * 4]) = vv;
    }
    __syncthreads();
    const int qi = threadIdx.x & 63, grp = threadIdx.x >> 6;
    const int hl = grp & 1, half = grp >> 1;
    f32x4* tp4 = (f32x4*)tP;
    const size_t base = (((size_t)(b * 32 + it) * 2 + hl) * 8 + half * 4) * 2048 + q0 + qi;
    #pragma unroll
    for (int jj2 = 0; jj2 < 4; jj2++) {
        f32x4 vv = *(const f32x4*)(&T[qi][32 * half + 8 * jj2 + 4 * hl]);
        tp4[base + (size_t)jj2 * 2048] = vv;
    }
}

// ---------------------------------------------------------------- fused QKV projection GEMM
// z selects (A, Bt, Cout, scale, epilogue): z<2 -> head-split [B,H,N,HD] (Q,K);
// z==2 -> transposed [B,H,HD,N] (V).  A/C stride 8M u16; Bt stride 1M u16.
__global__ __launch_bounds__(256) void gemm_qkv(const u16* __restrict__ Abase,
                                                const u16* __restrict__ Wbase,
                                                u16* __restrict__ Cbase) {
    __shared__ __align__(16) u16 lga[128 * 64];
    __shared__ __align__(16) u16 lgb[128 * 64];
    const int tid  = threadIdx.x;
    const int lane = tid & 63, wave = tid >> 6;
    const int wm = wave >> 1, wn = wave & 1;
    const int z = blockIdx.z;
    const u16* A  = Abase + (size_t)z * (8u << 20);
    const u16* Bt = Wbase + (size_t)z * (DIM_ * DIM_);
    u16* Cout     = Cbase + (size_t)z * (8u << 20);
    const float scale = (z == 0) ? QSCALE_ : 1.0f;
    int lin = blockIdx.x + gridDim.x * blockIdx.y;
    int w   = (lin & 7) * 64 + (lin >> 3);
    const int row0 = (w >> 3) * 128, col0 = (w & 7) * 128;

    f32x4 acc[4][4] = {};

    auto stageLds = [&](const u16* G, u16* L, int rowbase, int k0) {
        #pragma unroll
        for (int i = 0; i < 4; i++) {
            int rb = wave * 32 + i * 8;
            int r  = rb + (lane >> 3);
            int cc = (lane & 7) ^ (lane >> 3);
            gl_lds16(G + (size_t)(rowbase + r) * DIM_ + k0 + cc * 8, L + rb * 64);
        }
    };

    for (int k0 = 0; k0 < DIM_; k0 += 64) {
        stageLds(A,  lga, row0, k0);
        stageLds(Bt, lgb, col0, k0);
        __syncthreads();
        #pragma unroll
        for (int kk = 0; kk < 2; kk++) {
            s16x8 af[4], bfr[4];
            #pragma unroll
            for (int mi = 0; mi < 4; mi++) {
                int r = wm * 64 + mi * 16 + (lane & 15);
                int sc = (kk * 4 + (lane >> 4)) ^ (lane & 7);
                af[mi] = *(const s16x8*)(&lga[r * 64 + sc * 8]);
            }
            #pragma unroll
            for (int ni = 0; ni < 4; ni++) {
                int r = wn * 64 + ni * 16 + (lane & 15);
                int sc = (kk * 4 + (lane >> 4)) ^ (lane & 7);
                bfr[ni] = *(const s16x8*)(&lgb[r * 64 + sc * 8]);
            }
            #pragma unroll
            for (int mi = 0; mi < 4; mi++)
                #pragma unroll
                for (int ni = 0; ni < 4; ni++)
                    acc[mi][ni] = __builtin_amdgcn_mfma_f32_16x16x32_bf16(
                        af[mi], bfr[ni], acc[mi][ni], 0, 0, 0);
        }
        __syncthreads();
    }

    #pragma unroll
    for (int mi = 0; mi < 4; mi++) {
        #pragma unroll
        for (int ni = 0; ni < 4; ni++) {
            #pragma unroll
            for (int r = 0; r < 4; r++) {
                int grow = row0 + wm * 64 + mi * 16 + ((lane >> 4) << 2) + r;
                int gcol = col0 + wn * 64 + ni * 16 + (lane & 15);
                float vv = acc[mi][ni][r] * scale;
                int bb = grow >> 11, n = grow & (N_ - 1);
                int hh = gcol >> 7,  d = gcol & (HD_ - 1);
                size_t idx = (z < 2)
                    ? ((size_t)(bb * H_ + hh) * N_ + n) * HD_ + d
                    : ((size_t)(bb * H_ + hh) * HD_ + d) * N_ + n;
                Cout[idx] = f2bf(vv);
            }
        }
    }
}

// ---------------------------------------------------------------- output projection GEMM
__global__ __launch_bounds__(256) void gemm_out(const u16* __restrict__ A,
                                                const u16* __restrict__ Bt,
                                                float* __restrict__ Cout,
                                                const float* __restrict__ bias) {
    __shared__ __align__(16) u16 lga[128 * 64];
    __shared__ __align__(16) u16 lgb[128 * 64];
    const int tid  = threadIdx.x;
    const int lane = tid & 63, wave = tid >> 6;
    const int wm = wave >> 1, wn = wave & 1;
    int lin = blockIdx.x + gridDim.x * blockIdx.y;
    int w   = (lin & 7) * 64 + (lin >> 3);
    const int row0 = (w >> 3) * 128, col0 = (w & 7) * 128;

    f32x4 acc[4][4] = {};

    auto stageLds = [&](const u16* G, u16* L, int rowbase, int k0) {
        #pragma unroll
        for (int i = 0; i < 4; i++) {
            int rb = wave * 32 + i * 8;
            int r  = rb + (lane >> 3);
            int cc = (lane & 7) ^ (lane >> 3);
            gl_lds16(G + (size_t)(rowbase + r) * DIM_ + k0 + cc * 8, L + rb * 64);
        }
    };

    for (int k0 = 0; k0 < DIM_; k0 += 64) {
        stageLds(A,  lga, row0, k0);
        stageLds(Bt, lgb, col0, k0);
        __syncthreads();
        #pragma unroll
        for (int kk = 0; kk < 2; kk++) {
            s16x8 af[4], bfr[4];
            #pragma unroll
            for (int mi = 0; mi < 4; mi++) {
                int r = wm * 64 + mi * 16 + (lane & 15);
                int sc = (kk * 4 + (lane >> 4)) ^ (lane & 7);
                af[mi] = *(const s16x8*)(&lga[r * 64 + sc * 8]);
            }
            #pragma unroll
            for (int ni = 0; ni < 4; ni++) {
                int r = wn * 64 + ni * 16 + (lane & 15);
                int sc = (kk * 4 + (lane >> 4)) ^ (lane & 7);
                bfr[ni] = *(const s16x8*)(&lgb[r * 64 + sc * 8]);
            }
            #pragma unroll
            for (int mi = 0; mi < 4; mi++)
                #pragma unroll
                for (int ni = 0; ni < 4; ni++)
                    acc[mi][ni] = __builtin_amdgcn_mfma_f32_16x16x32_bf16(
                        af[mi], bfr[ni], acc[mi][ni], 0, 0, 0);
        }
        __syncthreads();
    }

    #pragma unroll
    for (int mi = 0; mi < 4; mi++) {
        #pragma unroll
        for (int ni = 0; ni < 4; ni++) {
            #pragma unroll
            for (int r = 0; r < 4; r++) {
                int grow = row0 + wm * 64 + mi * 16 + ((lane >> 4) << 2) + r;
                int gcol = col0 + wn * 64 + ni * 16 + (lane & 15);
                Cout[(size_t)grow * DIM_ + gcol] = acc[mi][ni][r] + bias[gcol];
            }
        }
    }
}

// ---------------------------------------------------------------- gated flash attention (swapped)
// R12-proven core (104.7 us): scalar softmax, lane-coalesced tP gate reads.
__global__ __launch_bounds__(256, 2) void attn_swapped(const u16* __restrict__ Qh,
                                                       const u16* __restrict__ Kh,
                                                       const u16* __restrict__ Vt,
                                                       const float* __restrict__ tP,
                                                       u16* __restrict__ xout) {
    __shared__ __align__(16) u16 kt[2][64 * 128];   // K [kv=64][d=128], slot = c ^ mK(r)
    __shared__ __align__(16) u16 vt[2][128 * 64];   // Vt [d=128][kv=64], slot = c ^ mV(r)

    const int tid = threadIdx.x, lane = tid & 63, wave = tid >> 6;
    const int lq = lane & 31, hl = lane >> 5;

    int lin = blockIdx.x + 16 * (blockIdx.y + 8 * blockIdx.z);
    int nl  = (lin & 7) * 64 + (lin >> 3);
    const int qt = nl & 15, hh = (nl >> 4) & 7, b = nl >> 7;
    const int q0 = qt * 128 + wave * 32;
    const int q  = q0 + lq;

    const u16* Qbh = Qh + (size_t)(b * H_ + hh) * N_ * HD_;
    const u16* Kbh = Kh + (size_t)(b * H_ + hh) * N_ * HD_;
    const u16* Vbh = Vt + (size_t)(b * H_ + hh) * HD_ * N_;
    // lane-coalesced gate base: tP4[(((b*32+it)*2+hl)*8 + jj)*2048 + q]
    const f32x4* tp4 = (const f32x4*)tP;
    const size_t tbase0 = ((size_t)(b * 32) * 2 + hl) * 8 * 2048 + q;

    s16x8 qf[8];
    #pragma unroll
    for (int s = 0; s < 8; s++)
        qf[s] = *(const s16x8*)(Qbh + (size_t)q * HD_ + s * 16 + hl * 8);

    auto stageKV = [&](int kv0, int bi) {
        #pragma unroll
        for (int i = 0; i < 4; i++) {
            int rk = wave * 16 + i * 4 + (lane >> 4);
            int ck = (lane & 15) ^ (rk & 15) ^ ((rk & 16) >> 2);
            gl_lds16(Kbh + (size_t)(kv0 + rk) * HD_ + ck * 8,
                     &kt[bi][(wave * 16 + i * 4) * 128]);
            int rv = wave * 32 + i * 8 + (lane >> 3);
            int cv = (lane & 7) ^ (rv & 7) ^ ((rv >> 3) & 3);
            gl_lds16(Vbh + (size_t)rv * N_ + kv0 + cv * 8,
                     &vt[bi][(wave * 32 + i * 8) * 64]);
        }
    };

    const int mKl = (lq & 15) ^ ((lq & 16) >> 2);
    const int mVl = (lq & 7) ^ ((lq >> 3) & 3);

    float m = -3.0e38f, l = 0.f;
    f32x16 aoT[4] = {};

    stageKV(0, 0);
    __syncthreads();

    for (int it = 0; it < N_ / 64; it++) {
        const int kv0 = it * 64, cur = it & 1;
        if (it + 1 < N_ / 64) stageKV(kv0 + 64, cur ^ 1);

        // gate values: 8 lane-coalesced f32x4 loads (32 lanes x 16B dense each)
        const size_t tbase = tbase0 + (size_t)it * (2 * 8 * 2048);
        f32x4 ttv[8];
        #pragma unroll
        for (int jj = 0; jj < 8; jj++)
            ttv[jj] = tp4[tbase + (size_t)jj * 2048];

        f32x16 sT[2] = {};
        __builtin_amdgcn_s_setprio(1);
        #pragma unroll
        for (int s = 0; s < 8; s++)
            #pragma unroll
            for (int ni = 0; ni < 2; ni++) {
                int r = ni * 32 + lq;
                int slot = (2 * s + hl) ^ mKl;
                s16x8 kf = *(const s16x8*)(&kt[cur][r * 128 + slot * 8]);
                sT[ni] = __builtin_amdgcn_mfma_f32_32x32x16_bf16(kf, qf[s], sT[ni], 0, 0, 0);
            }
        __builtin_amdgcn_s_setprio(0);

        float mx = -3.0e38f;
        #pragma unroll
        for (int ni = 0; ni < 2; ni++)
            #pragma unroll
            for (int idx = 0; idx < 16; idx++) {
                float g = sT[ni][idx] * ttv[(ni << 2) | (idx >> 2)][idx & 3];
                sT[ni][idx] = g;
                mx = fmaxf(mx, g);
            }
        mx = fmaxf(mx, __shfl_xor(mx, 32));

        if (__any(mx > m + 8.0f)) {
            float mn = fmaxf(m, mx);
            float sfv = __builtin_amdgcn_exp2f(m - mn);
            m = mn;
            l *= sfv;
            #pragma unroll
            for (int dt = 0; dt < 4; dt++)
                #pragma unroll
                for (int e = 0; e < 16; e++) aoT[dt][e] *= sfv;
        }

        float rs = 0.f;
        #pragma unroll
        for (int ni = 0; ni < 2; ni++)
            #pragma unroll
            for (int e = 0; e < 16; e++) {
                float g = sT[ni][e];
                float p = __builtin_amdgcn_exp2f(g - m);
                rs += p;
                sT[ni][e] = (g != 0.0f) ? p : 0.0f;
            }
        rs += __shfl_xor(rs, 32);
        l += rs;

        s16x8 pfrag[4];
        #pragma unroll
        for (int sp = 0; sp < 4; sp++) {
            const int ni = sp >> 1;
            const int ru = (2 * sp) & 3, rv2 = (2 * sp + 1) & 3;
            unsigned u0 = pk_bf16(sT[ni][ru * 4 + 0], sT[ni][ru * 4 + 1]);
            unsigned u1 = pk_bf16(sT[ni][ru * 4 + 2], sT[ni][ru * 4 + 3]);
            unsigned v0 = pk_bf16(sT[ni][rv2 * 4 + 0], sT[ni][rv2 * 4 + 1]);
            unsigned v1 = pk_bf16(sT[ni][rv2 * 4 + 2], sT[ni][rv2 * 4 + 3]);
            pl32_swap(u0, v0);
            pl32_swap(u1, v1);
            u32x4 w = {u0, u1, v0, v1};
            pfrag[sp] = __builtin_bit_cast(s16x8, w);
        }

        __builtin_amdgcn_s_setprio(1);
        #pragma unroll
        for (int dt = 0; dt < 4; dt++)
            #pragma unroll
            for (int sp = 0; sp < 4; sp++) {
                int r = dt * 32 + lq;
                int slot = (2 * sp + hl) ^ mVl;
                s16x8 vf = *(const s16x8*)(&vt[cur][r * 64 + slot * 8]);
                aoT[dt] = __builtin_amdgcn_mfma_f32_32x32x16_bf16(vf, pfrag[sp], aoT[dt], 0, 0, 0);
            }
        __builtin_amdgcn_s_setprio(0);
        __syncthreads();
    }

    float inv = 1.0f / l;
    u16* orow = xout + ((size_t)(b * N_ + q)) * DIM_ + hh * HD_;
    #pragma unroll
    for (int dt = 0; dt < 4; dt++)
        #pragma unroll
        for (int r2 = 0; r2 < 4; r2++) {
            u16x4 ov;
            #pragma unroll
            for (int e = 0; e < 4; e++)
                ov[e] = f2bf(aoT[dt][r2 * 4 + e] * inv);
            *(u16x4*)(orow + dt * 32 + r2 * 8 + hl * 4) = ov;
        }
}

// ---------------------------------------------------------------- launch
extern "C" void kernel_launch(void* const* d_in, const int* in_sizes, int n_in,
                              void* d_out, int out_size, void* d_ws, size_t ws_size,
                              hipStream_t stream) {
    const float* q     = (const float*)d_in[0];
    const float* k     = (const float*)d_in[1];
    const float* v     = (const float*)d_in[2];
    const float* trans = (const float*)d_in[3];
    const float* Wq    = (const float*)d_in[4];
    const float* Wk    = (const float*)d_in[5];
    const float* Wv    = (const float*)d_in[6];
    const float* Wp    = (const float*)d_in[7];
    const float* bp    = (const float*)d_in[8];
    float* out         = (float*)d_out;

    // workspace map (136 MiB):
    //  [0,16M): xb attention output bf16
    //  [16M..24M): Wq,Wk,Wv,Wp bf16 (contiguous) ; [24..72M): Qh/Kh/Vt (stride 16 MiB)
    //  [72M..120M): qb/kb/vb bf16 (stride 16 MiB; dead after projections)
    //  [72M..136M): tP permuted gates (written by gate_permute AFTER projections
    //               consumed qb/kb/vb — ordering makes the overlap safe)
    char* ws = (char*)d_ws;
    u16* xb  = (u16*)(ws);
    u16* wqb = (u16*)(ws + (16u << 20));
    u16* wpb = (u16*)(ws + (22u << 20));
    u16* QhB = (u16*)(ws + (24u << 20));
    u16* KhB = (u16*)(ws + (40u << 20));
    u16* VtB = (u16*)(ws + (56u << 20));
    u16* qb  = (u16*)(ws + (72u << 20));
    float* tP = (float*)(ws + (72u << 20));

    dim3 blk(256);
    prep<<<dim3(14336), blk, 0, stream>>>(q, k, v, Wq, Wk, Wv, Wp, qb, wqb);
    gemm_qkv<<<dim3(8, 64, 3), blk, 0, stream>>>(qb, wqb, QhB);
    gate_permute<<<dim3(4096), blk, 0, stream>>>(trans, tP);
    attn_swapped<<<dim3(16, 8, 4), blk, 0, stream>>>(QhB, KhB, VtB, tP, xb);
    gemm_out<<<dim3(DIM_ / 128, MTOK / 128), blk, 0, stream>>>(xb, wpb, out, bp);
}